// Round 7
// baseline (1354.621 us; speedup 1.0000x reference)
//
#include <hip/hip_runtime.h>
#include <hip/hip_bf16.h>

static constexpr int N = 512;    // state size == feature size
static constexpr int L = 16384;  // sequence length
static constexpr int SQX = 16;   // sq blocks occupy bx < SQX in MODE 0

typedef short s16x8 __attribute__((ext_vector_type(8)));
typedef float f32x4 __attribute__((ext_vector_type(4)));
using bf16 = __hip_bfloat16;

__device__ __forceinline__ void split2(float v, ushort& h, ushort& l) {
    bf16 hb = __float2bfloat16(v);
    h = *reinterpret_cast<ushort*>(&hb);
    bf16 lb = __float2bfloat16(v - __bfloat162float(hb));
    l = *reinterpret_cast<ushort*>(&lb);
}
__device__ __forceinline__ float b2f(bf16 x) { return __bfloat162float(x); }

// ---------------- small setup kernels ----------------

__global__ void k_scale(const float* __restrict__ A, float* __restrict__ M, float h, int n) {
    int i = blockIdx.x * 256 + threadIdx.x;
    if (i < n) M[i] = A[i] * h;
}

// D0 = 2(M+M^2) (f32 + split), BL = I + M + M^2
__global__ void k_buildD(const float* __restrict__ M, const float* __restrict__ M2,
                         float* __restrict__ D0f, bf16* __restrict__ Dh,
                         bf16* __restrict__ Dl, float* __restrict__ BLm) {
    int i = blockIdx.x * 256 + threadIdx.x;
    if (i >= N * N) return;
    float m = M[i], m2 = M2[i];
    float d = 2.0f * (m + m2);
    D0f[i] = d;
    ushort h, l;
    split2(d, h, l);
    *reinterpret_cast<ushort*>(Dh + i) = h;
    *reinterpret_cast<ushort*>(Dl + i) = l;
    BLm[i] = (((i >> 9) == (i & (N - 1))) ? 1.0f : 0.0f) + m + m2;
}

// vectorized f32 -> (hi, lo) bf16 split, 4 elems/thread
__global__ void k_split4(const float* __restrict__ in, bf16* __restrict__ hi,
                         bf16* __restrict__ lo, int n4) {
    int i = blockIdx.x * 256 + threadIdx.x;
    if (i >= n4) return;
    float4 v = reinterpret_cast<const float4*>(in)[i];
    ushort ht[4], lt[4];
    split2(v.x, ht[0], lt[0]);
    split2(v.y, ht[1], lt[1]);
    split2(v.z, ht[2], lt[2]);
    split2(v.w, ht[3], lt[3]);
    *reinterpret_cast<ushort4*>(hi + 4 * (size_t)i) = *reinterpret_cast<ushort4*>(ht);
    *reinterpret_cast<ushort4*>(lo + 4 * (size_t)i) = *reinterpret_cast<ushort4*>(lt);
}

// 512x512 f32 transpose
__global__ void k_transpose(const float* __restrict__ in, float* __restrict__ out) {
    __shared__ float t[32][33];
    int bx = blockIdx.x * 32, by = blockIdx.y * 32;
    int tx = threadIdx.x, ty = threadIdx.y;  // block 32x8
#pragma unroll
    for (int j = 0; j < 32; j += 8) t[ty + j][tx] = in[(by + ty + j) * N + bx + tx];
    __syncthreads();
#pragma unroll
    for (int j = 0; j < 32; j += 8) out[(bx + ty + j) * N + by + tx] = t[tx][ty + j];
}

// transpose + f32 master + bf16 split of the transpose
__global__ void k_tsplit(const float* __restrict__ in, float* __restrict__ of,
                         bf16* __restrict__ oh, bf16* __restrict__ ol) {
    __shared__ float t[32][33];
    int bx = blockIdx.x * 32, by = blockIdx.y * 32;
    int tx = threadIdx.x, ty = threadIdx.y;
#pragma unroll
    for (int j = 0; j < 32; j += 8) t[ty + j][tx] = in[(by + ty + j) * N + bx + tx];
    __syncthreads();
#pragma unroll
    for (int j = 0; j < 32; j += 8) {
        float v = t[tx][ty + j];
        size_t off = (size_t)(bx + ty + j) * N + by + tx;
        of[off] = v;
        ushort h, l;
        split2(v, h, l);
        *reinterpret_cast<ushort*>(oh + off) = h;
        *reinterpret_cast<ushort*>(ol + off) = l;
    }
}

// ---------------- f32 NT GEMM 64x64 + fused bf16-split epilogue (setup only) ----
__global__ __launch_bounds__(256) void k_qsq(
    const float* __restrict__ Asrc, const float* __restrict__ Bmat,
    float* __restrict__ OUT, bf16* __restrict__ Sh, bf16* __restrict__ Sl, float scale) {
    __shared__ float As[32][64];
    __shared__ float Bs[32][64];
    const int tid = threadIdx.x;
    const int brow = blockIdx.x * 64;
    const int bcol = blockIdx.y * 64;
    const int tx = tid & 15, ty = tid >> 4;
    float acc[4][4] = {};

    for (int k0 = 0; k0 < N; k0 += 32) {
#pragma unroll
        for (int q = 0; q < 2; ++q) {
            int idx = tid * 2 + q;
            int row = idx >> 3;
            int kq = (idx & 7) << 2;
            float4 va = *(const float4*)(Asrc + (long)(brow + row) * N + k0 + kq);
            As[kq + 0][row] = va.x; As[kq + 1][row] = va.y;
            As[kq + 2][row] = va.z; As[kq + 3][row] = va.w;
            float4 vb = *(const float4*)(Bmat + (long)(bcol + row) * N + k0 + kq);
            Bs[kq + 0][row] = vb.x; Bs[kq + 1][row] = vb.y;
            Bs[kq + 2][row] = vb.z; Bs[kq + 3][row] = vb.w;
        }
        __syncthreads();
#pragma unroll
        for (int kk = 0; kk < 32; ++kk) {
            float a[4], b[4];
            *(float4*)&a[0] = *(const float4*)&As[kk][ty * 4];
            *(float4*)&b[0] = *(const float4*)&Bs[kk][tx * 4];
#pragma unroll
            for (int i = 0; i < 4; ++i)
#pragma unroll
                for (int j = 0; j < 4; ++j) acc[i][j] = fmaf(a[i], b[j], acc[i][j]);
        }
        __syncthreads();
    }
#pragma unroll
    for (int i = 0; i < 4; ++i) {
        long off = (long)(brow + ty * 4 + i) * N + bcol + tx * 4;
        float4 o = make_float4(acc[i][0] * scale, acc[i][1] * scale,
                               acc[i][2] * scale, acc[i][3] * scale);
        *(float4*)(OUT + off) = o;
        ushort ht[4], lt[4];
        split2(o.x, ht[0], lt[0]); split2(o.y, ht[1], lt[1]);
        split2(o.z, ht[2], lt[2]); split2(o.w, ht[3], lt[3]);
        *reinterpret_cast<ushort4*>(Sh + off) = *reinterpret_cast<ushort4*>(ht);
        *reinterpret_cast<ushort4*>(Sl + off) = *reinterpret_cast<ushort4*>(lt);
    }
}

// ---------------- main MFMA kernel: LDS-free, barrier-free direct-fragment GEMM --
// X stored as bf16 (hi,lo) pair.  Fragment layout for mfma_16x16x32_bf16:
//   lane l of a-frag = A[row_base + (l&15)][k0 + (l>>4)*8 .. +8]  -> one dwordx4.
// MODE 0 (round): bx<SQX: Dnext = D^2+2D sq blocks; else
//   Xo[i] = Xi[i] + Xi[i-s] + (Xi[i-s] @ D^T)[i]; rows rotated so copies last.
// MODE 1 (plain): out = Xi @ Bp^T  (pair out, or f32 out if OUTF32).
// NM=1: single MFMA (hi*hi); NM=3: bf16x3. MASK: per-lane zero for rows < 0.
template <int NM, int MODE, bool OUTF32, bool MASK>
__global__ __launch_bounds__(256, (NM == 1 ? 3 : 2)) void k_gemm(
    const bf16* __restrict__ Xih, const bf16* __restrict__ Xil,
    bf16* __restrict__ Xoh, bf16* __restrict__ Xol, float* __restrict__ Of,
    const bf16* __restrict__ Bph, const bf16* __restrict__ Bpl,
    const bf16* __restrict__ DTh, const bf16* __restrict__ DTl,
    const float* __restrict__ DTf,
    bf16* __restrict__ Dnh, bf16* __restrict__ Dnl,
    bf16* __restrict__ DTnh, bf16* __restrict__ DTnl, float* __restrict__ DTfn,
    int shift, int doSq)
{
    const int tid = threadIdx.x;
    const int wave = tid >> 6, lane = tid & 63;
    const int wm = wave >> 1, wn = wave & 1;
    const int rl = lane & 15, rh = lane >> 4;

    if (MODE == 0 && blockIdx.x < SQX) {
        // ======== D-squaring (64 blocks, dispatched first, LDS-free) ========
        if (!doSq) return;
        int sidx = (int)blockIdx.x * (int)gridDim.y + (int)blockIdx.y;  // 0..63
        const int ti = (sidx >> 3) * 64, tj = (sidx & 7) * 64;

        f32x4 acc[2][2];
#pragma unroll
        for (int m = 0; m < 2; ++m)
#pragma unroll
            for (int n = 0; n < 2; ++n) acc[m][n] = (f32x4){0.f, 0.f, 0.f, 0.f};

        int oa[2], ob[2];
#pragma unroll
        for (int m = 0; m < 2; ++m) oa[m] = (ti + wm * 32 + m * 16 + rl) * N + rh * 8;
#pragma unroll
        for (int n = 0; n < 2; ++n) ob[n] = (tj + wn * 32 + n * 16 + rl) * N + rh * 8;

#pragma unroll
        for (int t = 0; t < 16; ++t) {
            s16x8 ah[2], al[2], bh[2], bl[2];
#pragma unroll
            for (int m = 0; m < 2; ++m) {
                ah[m] = *reinterpret_cast<const s16x8*>(DTh + oa[m] + t * 32);
                al[m] = *reinterpret_cast<const s16x8*>(DTl + oa[m] + t * 32);
            }
#pragma unroll
            for (int n = 0; n < 2; ++n) {
                bh[n] = *reinterpret_cast<const s16x8*>(Bph + ob[n] + t * 32);
                bl[n] = *reinterpret_cast<const s16x8*>(Bpl + ob[n] + t * 32);
            }
#pragma unroll
            for (int m = 0; m < 2; ++m)
#pragma unroll
                for (int n = 0; n < 2; ++n) {
                    acc[m][n] = __builtin_amdgcn_mfma_f32_16x16x32_bf16(ah[m], bh[n], acc[m][n], 0, 0, 0);
                    acc[m][n] = __builtin_amdgcn_mfma_f32_16x16x32_bf16(ah[m], bl[n], acc[m][n], 0, 0, 0);
                    acc[m][n] = __builtin_amdgcn_mfma_f32_16x16x32_bf16(al[m], bh[n], acc[m][n], 0, 0, 0);
                }
        }

#pragma unroll
        for (int m = 0; m < 2; ++m)
#pragma unroll
            for (int n = 0; n < 2; ++n)
#pragma unroll
                for (int q = 0; q < 4; ++q) {
                    int i = ti + wm * 32 + m * 16 + rh * 4 + q;
                    int j = tj + wn * 32 + n * 16 + rl;
                    size_t off = (size_t)i * N + j;
                    float v = acc[m][n][q] + 2.0f * DTf[off];   // (D^2)^T + 2 D^T
                    DTfn[off] = v;
                    ushort h, l;
                    split2(v, h, l);
                    *reinterpret_cast<ushort*>(DTnh + off) = h;
                    *reinterpret_cast<ushort*>(DTnl + off) = l;
                    size_t offT = (size_t)j * N + i;
                    *reinterpret_cast<ushort*>(Dnh + offT) = h;
                    *reinterpret_cast<ushort*>(Dnl + offT) = l;
                }
        return;
    }

    // ======== big path (rows rotated so GEMM blocks dispatch first) ========
    int bigbx = (MODE == 0) ? ((int)blockIdx.x - SQX) : (int)blockIdx.x;
    const int sb = (MODE == 0) ? (shift >> 7) : 0;
    int rowBlk = bigbx + sb;
    bool isCopy = false;
    if (MODE == 0 && rowBlk >= (L / 128)) { rowBlk -= (L / 128); isCopy = true; }
    const long brow = (long)rowBlk * 128;
    const int bcol = blockIdx.y * 128;

    if (MODE == 0 && isCopy) {
        // rows fully below shift: Xo = Xi (pair copy)
#pragma unroll
        for (int j = 0; j < 8; ++j) {
            int c = j * 256 + tid;
            long off = (brow + (c >> 4)) * N + bcol + (c & 15) * 8;
            *reinterpret_cast<int4*>(Xoh + off) = *reinterpret_cast<const int4*>(Xih + off);
            *reinterpret_cast<int4*>(Xol + off) = *reinterpret_cast<const int4*>(Xil + off);
        }
        return;
    }

    f32x4 acc[4][4];
#pragma unroll
    for (int m = 0; m < 4; ++m)
#pragma unroll
        for (int n = 0; n < 4; ++n) acc[m][n] = (f32x4){0.f, 0.f, 0.f, 0.f};

    // per-fragment base offsets (fold into saddr + voffset + imm)
    int oa[4]; bool va[4]; int ob[4];
#pragma unroll
    for (int m = 0; m < 4; ++m) {
        long grow = brow - (MODE == 0 ? (long)shift : 0) + wm * 64 + m * 16 + rl;
        va[m] = (grow >= 0);
        if (grow < 0) grow = 0;
        oa[m] = (int)(grow * N) + rh * 8;
    }
#pragma unroll
    for (int n = 0; n < 4; ++n) ob[n] = (bcol + wn * 64 + n * 16 + rl) * N + rh * 8;

    const s16x8 zf = {0, 0, 0, 0, 0, 0, 0, 0};

#pragma unroll
    for (int t = 0; t < 16; ++t) {
        s16x8 ah[4], bh[4];
#pragma unroll
        for (int m = 0; m < 4; ++m) {
            ah[m] = *reinterpret_cast<const s16x8*>(Xih + oa[m] + t * 32);
            if (MASK) ah[m] = va[m] ? ah[m] : zf;
        }
#pragma unroll
        for (int n = 0; n < 4; ++n)
            bh[n] = *reinterpret_cast<const s16x8*>(Bph + ob[n] + t * 32);

        if constexpr (NM == 1) {
#pragma unroll
            for (int m = 0; m < 4; ++m)
#pragma unroll
                for (int n = 0; n < 4; ++n)
                    acc[m][n] = __builtin_amdgcn_mfma_f32_16x16x32_bf16(ah[m], bh[n], acc[m][n], 0, 0, 0);
        } else {
            s16x8 al[4], bl[4];
#pragma unroll
            for (int m = 0; m < 4; ++m) {
                al[m] = *reinterpret_cast<const s16x8*>(Xil + oa[m] + t * 32);
                if (MASK) al[m] = va[m] ? al[m] : zf;
            }
#pragma unroll
            for (int n = 0; n < 4; ++n)
                bl[n] = *reinterpret_cast<const s16x8*>(Bpl + ob[n] + t * 32);
#pragma unroll
            for (int m = 0; m < 4; ++m)
#pragma unroll
                for (int n = 0; n < 4; ++n) {
                    acc[m][n] = __builtin_amdgcn_mfma_f32_16x16x32_bf16(ah[m], bh[n], acc[m][n], 0, 0, 0);
                    acc[m][n] = __builtin_amdgcn_mfma_f32_16x16x32_bf16(ah[m], bl[n], acc[m][n], 0, 0, 0);
                    acc[m][n] = __builtin_amdgcn_mfma_f32_16x16x32_bf16(al[m], bh[n], acc[m][n], 0, 0, 0);
                }
        }
    }

    // epilogue: C/D layout col=lane&15, row=(lane>>4)*4+reg
    const long orow0 = brow + wm * 64;
    const int ocol0 = bcol + wn * 64;
#pragma unroll
    for (int m = 0; m < 4; ++m) {
#pragma unroll
        for (int q = 0; q < 4; ++q) {
            long gi = orow0 + m * 16 + rh * 4 + q;
            long base = gi * N + ocol0 + rl;
            if (MODE == 0) {
                bool hasS = (gi >= (long)shift);
                long base2 = base - (long)shift * N;
#pragma unroll
                for (int n = 0; n < 4; ++n) {
                    long off = base + n * 16;
                    float v = acc[m][n][q] + b2f(Xih[off]) + b2f(Xil[off]);
                    if (hasS) {
                        long o2 = base2 + n * 16;
                        v += b2f(Xih[o2]) + b2f(Xil[o2]);
                    }
                    ushort h, l;
                    split2(v, h, l);
                    *reinterpret_cast<ushort*>(Xoh + off) = h;
                    *reinterpret_cast<ushort*>(Xol + off) = l;
                }
            } else {
#pragma unroll
                for (int n = 0; n < 4; ++n) {
                    long off = base + n * 16;
                    if (OUTF32) {
                        Of[off] = acc[m][n][q];
                    } else {
                        ushort h, l;
                        split2(acc[m][n][q], h, l);
                        *reinterpret_cast<ushort*>(Xoh + off) = h;
                        *reinterpret_cast<ushort*>(Xol + off) = l;
                    }
                }
            }
        }
    }
}

// ---------------- launcher ----------------

extern "C" void kernel_launch(void* const* d_in, const int* in_sizes, int n_in,
                              void* d_out, int out_size, void* d_ws, size_t ws_size,
                              hipStream_t stream) {
    (void)in_sizes; (void)n_in; (void)out_size; (void)ws_size;
    const float* A = (const float*)d_in[0];
    const float* B = (const float*)d_in[1];
    const float* C = (const float*)d_in[2];
    const float* u = (const float*)d_in[3];

    const size_t NN = (size_t)N * N;
    const size_t LN = (size_t)L * N;

    // X1 pair lives in d_out (2 x 16MB bf16 == 32MB f32 out buffer)
    bf16* X1h = (bf16*)d_out;
    bf16* X1l = X1h + LN;

    char* w = (char*)d_ws;
    bf16* X0h = (bf16*)w;      w += LN * 2;
    bf16* X0l = (bf16*)w;      w += LN * 2;
    bf16 *Dh_[2], *Dl_[2], *DTh_[2], *DTl_[2];
    float* DTf_[2];
    for (int s = 0; s < 2; ++s) {
        Dh_[s]  = (bf16*)w;    w += NN * 2;
        Dl_[s]  = (bf16*)w;    w += NN * 2;
        DTh_[s] = (bf16*)w;    w += NN * 2;
        DTl_[s] = (bf16*)w;    w += NN * 2;
        DTf_[s] = (float*)w;   w += NN * 4;
    }
    float* M   = (float*)w;    w += NN * 4;
    float* MT  = (float*)w;    w += NN * 4;
    float* M2  = (float*)w;    w += NN * 4;
    float* BLm = (float*)w;    w += NN * 4;
    float* BT  = (float*)w;    w += NN * 4;
    float* Bbf = (float*)w;    w += NN * 4;
    float* D0f = (float*)w;    w += NN * 4;
    bf16* Bbh  = (bf16*)w;     w += NN * 2;
    bf16* Bbl  = (bf16*)w;     w += NN * 2;
    bf16* Ch   = (bf16*)w;     w += NN * 2;
    bf16* Cl   = (bf16*)w;     w += NN * 2;

    const float step = 1.0f / (float)L;

    dim3 b256(256);
    dim3 gEl((int)((NN + 255) / 256));
    dim3 bT(32, 8), gT(N / 32, N / 32);
    dim3 g64(N / 64, N / 64);
    dim3 gBig(L / 128, N / 128);
    dim3 gRound(SQX + L / 128, N / 128);   // sq blocks first, then 128 big rows
    dim3 gS4n((int)(NN / 4 / 256));
    dim3 gS4L((int)(LN / 4 / 256));

    // ---- setup ----
    k_scale<<<gEl, b256, 0, stream>>>(A, M, step * 0.5f, (int)NN);
    k_transpose<<<gT, bT, 0, stream>>>(M, MT);
    k_qsq<<<g64, b256, 0, stream>>>(M, MT, M2, Bbh, Bbl, 1.0f);             // M2 = M@M (splits scratch)
    k_buildD<<<gEl, b256, 0, stream>>>(M, M2, D0f, Dh_[0], Dl_[0], BLm);    // D_0, BL
    k_tsplit<<<gT, bT, 0, stream>>>(D0f, DTf_[0], DTh_[0], DTl_[0]);        // D_0^T
    k_transpose<<<gT, bT, 0, stream>>>(B, BT);
    k_qsq<<<g64, b256, 0, stream>>>(BLm, BT, Bbf, Bbh, Bbl, step);          // Bb (+ split)
    k_split4<<<gS4n, b256, 0, stream>>>(C, Ch, Cl, (int)(NN / 4));
    k_split4<<<gS4L, b256, 0, stream>>>(u, X1h, X1l, (int)(LN / 4));        // u pair -> X1

    // ---- Bu = u @ Bb^T -> X0 pair ----
    k_gemm<3, 1, false, false><<<gBig, b256, 0, stream>>>(
        X1h, X1l, X0h, X0l, nullptr, Bbh, Bbl,
        nullptr, nullptr, nullptr, nullptr, nullptr, nullptr, nullptr, nullptr, 0, 0);

    // ---- 14 doubling rounds (D_{r+1} squaring fused, sq blocks first) ----
    for (int r = 0; r < 14; ++r) {
        int s = r & 1, nx = s ^ 1;
        bf16* Xih = (r & 1) ? X1h : X0h;  bf16* Xil = (r & 1) ? X1l : X0l;
        bf16* Xoh = (r & 1) ? X0h : X1h;  bf16* Xol = (r & 1) ? X0l : X1l;
        int doSq = (r < 13) ? 1 : 0;
        if (r < 7)
            k_gemm<1, 0, false, true><<<gRound, b256, 0, stream>>>(
                Xih, Xil, Xoh, Xol, nullptr, Dh_[s], Dl_[s],
                DTh_[s], DTl_[s], DTf_[s],
                Dh_[nx], Dl_[nx], DTh_[nx], DTl_[nx], DTf_[nx], 1 << r, doSq);
        else if (r < 10)
            k_gemm<1, 0, false, false><<<gRound, b256, 0, stream>>>(
                Xih, Xil, Xoh, Xol, nullptr, Dh_[s], Dl_[s],
                DTh_[s], DTl_[s], DTf_[s],
                Dh_[nx], Dl_[nx], DTh_[nx], DTl_[nx], DTf_[nx], 1 << r, doSq);
        else
            k_gemm<3, 0, false, false><<<gRound, b256, 0, stream>>>(
                Xih, Xil, Xoh, Xol, nullptr, Dh_[s], Dl_[s],
                DTh_[s], DTl_[s], DTf_[s],
                Dh_[nx], Dl_[nx], DTh_[nx], DTl_[nx], DTf_[nx], 1 << r, doSq);
    }

    // ---- final: OUT = X0 @ C^T (f32, overwrites d_out; X1 no longer needed) ----
    k_gemm<3, 1, true, false><<<gBig, b256, 0, stream>>>(
        X0h, X0l, nullptr, nullptr, (float*)d_out, Ch, Cl,
        nullptr, nullptr, nullptr, nullptr, nullptr, nullptr, nullptr, nullptr, 0, 0);
}

// Round 8
// 804.583 us; speedup vs baseline: 1.6836x; 1.6836x over previous
//
#include <hip/hip_runtime.h>
#include <hip/hip_bf16.h>

static constexpr int N = 512;    // state size == feature size
static constexpr int L = 16384;  // sequence length
static constexpr int SQX = 16;   // sq blocks occupy bx < SQX in MODE 0

typedef short s16x8 __attribute__((ext_vector_type(8)));
typedef float f32x4 __attribute__((ext_vector_type(4)));
using bf16 = __hip_bfloat16;

#define GPTR(p) ((const __attribute__((address_space(1))) void*)(p))
#define LPTR(p) ((__attribute__((address_space(3))) void*)(p))
__device__ __forceinline__ void gload16(const void* g, void* l) {
    __builtin_amdgcn_global_load_lds(GPTR(g), LPTR(l), 16, 0, 0);
}

__device__ __forceinline__ void split2(float v, ushort& h, ushort& l) {
    bf16 hb = __float2bfloat16(v);
    h = *reinterpret_cast<ushort*>(&hb);
    bf16 lb = __float2bfloat16(v - __bfloat162float(hb));
    l = *reinterpret_cast<ushort*>(&lb);
}
__device__ __forceinline__ float b2f(bf16 x) { return __bfloat162float(x); }

// ---------------- small setup kernels ----------------

__global__ void k_zeroinit(int* zb) { zb[blockIdx.x * 256 + threadIdx.x] = 0; }

__global__ void k_scale(const float* __restrict__ A, float* __restrict__ M, float h, int n) {
    int i = blockIdx.x * 256 + threadIdx.x;
    if (i < n) M[i] = A[i] * h;
}

// D0 = 2(M+M^2) (f32 + split), BL = I + M + M^2
__global__ void k_buildD(const float* __restrict__ M, const float* __restrict__ M2,
                         float* __restrict__ D0f, bf16* __restrict__ Dh,
                         bf16* __restrict__ Dl, float* __restrict__ BLm) {
    int i = blockIdx.x * 256 + threadIdx.x;
    if (i >= N * N) return;
    float m = M[i], m2 = M2[i];
    float d = 2.0f * (m + m2);
    D0f[i] = d;
    ushort h, l;
    split2(d, h, l);
    *reinterpret_cast<ushort*>(Dh + i) = h;
    *reinterpret_cast<ushort*>(Dl + i) = l;
    BLm[i] = (((i >> 9) == (i & (N - 1))) ? 1.0f : 0.0f) + m + m2;
}

// vectorized f32 -> (hi, lo) bf16 split, 4 elems/thread
__global__ void k_split4(const float* __restrict__ in, bf16* __restrict__ hi,
                         bf16* __restrict__ lo, int n4) {
    int i = blockIdx.x * 256 + threadIdx.x;
    if (i >= n4) return;
    float4 v = reinterpret_cast<const float4*>(in)[i];
    ushort ht[4], lt[4];
    split2(v.x, ht[0], lt[0]);
    split2(v.y, ht[1], lt[1]);
    split2(v.z, ht[2], lt[2]);
    split2(v.w, ht[3], lt[3]);
    *reinterpret_cast<ushort4*>(hi + 4 * (size_t)i) = *reinterpret_cast<ushort4*>(ht);
    *reinterpret_cast<ushort4*>(lo + 4 * (size_t)i) = *reinterpret_cast<ushort4*>(lt);
}

// 512x512 f32 transpose
__global__ void k_transpose(const float* __restrict__ in, float* __restrict__ out) {
    __shared__ float t[32][33];
    int bx = blockIdx.x * 32, by = blockIdx.y * 32;
    int tx = threadIdx.x, ty = threadIdx.y;  // block 32x8
#pragma unroll
    for (int j = 0; j < 32; j += 8) t[ty + j][tx] = in[(by + ty + j) * N + bx + tx];
    __syncthreads();
#pragma unroll
    for (int j = 0; j < 32; j += 8) out[(bx + ty + j) * N + by + tx] = t[tx][ty + j];
}

// transpose + f32 master + bf16 split of the transpose
__global__ void k_tsplit(const float* __restrict__ in, float* __restrict__ of,
                         bf16* __restrict__ oh, bf16* __restrict__ ol) {
    __shared__ float t[32][33];
    int bx = blockIdx.x * 32, by = blockIdx.y * 32;
    int tx = threadIdx.x, ty = threadIdx.y;
#pragma unroll
    for (int j = 0; j < 32; j += 8) t[ty + j][tx] = in[(by + ty + j) * N + bx + tx];
    __syncthreads();
#pragma unroll
    for (int j = 0; j < 32; j += 8) {
        float v = t[tx][ty + j];
        size_t off = (size_t)(bx + ty + j) * N + by + tx;
        of[off] = v;
        ushort h, l;
        split2(v, h, l);
        *reinterpret_cast<ushort*>(oh + off) = h;
        *reinterpret_cast<ushort*>(ol + off) = l;
    }
}

// ---------------- f32 NT GEMM 64x64 + fused bf16-split epilogue (setup only) ----
__global__ __launch_bounds__(256) void k_qsq(
    const float* __restrict__ Asrc, const float* __restrict__ Bmat,
    float* __restrict__ OUT, bf16* __restrict__ Sh, bf16* __restrict__ Sl, float scale) {
    __shared__ float As[32][64];
    __shared__ float Bs[32][64];
    const int tid = threadIdx.x;
    const int brow = blockIdx.x * 64;
    const int bcol = blockIdx.y * 64;
    const int tx = tid & 15, ty = tid >> 4;
    float acc[4][4] = {};

    for (int k0 = 0; k0 < N; k0 += 32) {
#pragma unroll
        for (int q = 0; q < 2; ++q) {
            int idx = tid * 2 + q;
            int row = idx >> 3;
            int kq = (idx & 7) << 2;
            float4 va = *(const float4*)(Asrc + (long)(brow + row) * N + k0 + kq);
            As[kq + 0][row] = va.x; As[kq + 1][row] = va.y;
            As[kq + 2][row] = va.z; As[kq + 3][row] = va.w;
            float4 vb = *(const float4*)(Bmat + (long)(bcol + row) * N + k0 + kq);
            Bs[kq + 0][row] = vb.x; Bs[kq + 1][row] = vb.y;
            Bs[kq + 2][row] = vb.z; Bs[kq + 3][row] = vb.w;
        }
        __syncthreads();
#pragma unroll
        for (int kk = 0; kk < 32; ++kk) {
            float a[4], b[4];
            *(float4*)&a[0] = *(const float4*)&As[kk][ty * 4];
            *(float4*)&b[0] = *(const float4*)&Bs[kk][tx * 4];
#pragma unroll
            for (int i = 0; i < 4; ++i)
#pragma unroll
                for (int j = 0; j < 4; ++j) acc[i][j] = fmaf(a[i], b[j], acc[i][j]);
        }
        __syncthreads();
    }
#pragma unroll
    for (int i = 0; i < 4; ++i) {
        long off = (long)(brow + ty * 4 + i) * N + bcol + tx * 4;
        float4 o = make_float4(acc[i][0] * scale, acc[i][1] * scale,
                               acc[i][2] * scale, acc[i][3] * scale);
        *(float4*)(OUT + off) = o;
        ushort ht[4], lt[4];
        split2(o.x, ht[0], lt[0]); split2(o.y, ht[1], lt[1]);
        split2(o.z, ht[2], lt[2]); split2(o.w, ht[3], lt[3]);
        *reinterpret_cast<ushort4*>(Sh + off) = *reinterpret_cast<ushort4*>(ht);
        *reinterpret_cast<ushort4*>(Sl + off) = *reinterpret_cast<ushort4*>(lt);
    }
}

// ---------------- main MFMA kernel (round-3 verified structure) ----------------
// 128x128 tile, 2x2 waves, BK=32, double-buffered LDS staged via global_load_lds
// with pre-swizzled source (slot' = slot ^ ((row>>1)&3)); 1 barrier per K-step.
// MODE 0 (round): bx<SQX: sq blocks Dnext = D^2 + 2D (f32 master DTf);
//   big blocks: Xo[i] = Xi[i] + Xi[i-s] + (Xi[i-s] @ D^T)[i]; rows rotated so
//   copy rows (fully below shift) dispatch last as pure pair-copies.
// MODE 1 (plain): out = Xi @ B^T (pair out, or f32 if OUTF32).
// NM=1: single MFMA (hi*hi) — D-form error ~2^-8*|D|*|X|, fine for r<10.
// NM=3: bf16x3 (hi*hi + hi*lo + lo*hi).
template <int NM, int MODE, bool OUTF32>
__global__ __launch_bounds__(256, (NM == 1 ? 3 : 2)) void k_round(
    const bf16* __restrict__ Xih, const bf16* __restrict__ Xil,
    bf16* __restrict__ Xoh, bf16* __restrict__ Xol, float* __restrict__ Of,
    const bf16* __restrict__ Dh, const bf16* __restrict__ Dl,
    const bf16* __restrict__ DTh, const bf16* __restrict__ DTl,
    const float* __restrict__ DTf,
    bf16* __restrict__ Dnh, bf16* __restrict__ Dnl,
    bf16* __restrict__ DTnh, bf16* __restrict__ DTnl, float* __restrict__ DTfn,
    int shift, int doSq, const bf16* __restrict__ zb)
{
    constexpr int LB = (NM == 1 ? 16384 : 32768);   // bytes per LDS buffer
    constexpr int BO = (NM == 1 ? 8192 : 16384);    // B-hi region offset
    __shared__ char smem[2 * LB];
    const int tid = threadIdx.x;
    const int wave = tid >> 6, lane = tid & 63;
    const int wm = wave >> 1, wn = wave & 1;
    const int rl = lane & 15, rh = lane >> 4;

    if (MODE == 0 && blockIdx.x < SQX) {
        // ======== D-squaring path (64 blocks, dispatched first) ========
        if (!doSq) return;
        int sidx = (int)blockIdx.x * (int)gridDim.y + (int)blockIdx.y;  // 0..63
        const int ti = (sidx >> 3) * 64, tj = (sidx & 7) * 64;

        f32x4 acc[2][2];
#pragma unroll
        for (int m = 0; m < 2; ++m)
#pragma unroll
            for (int n = 0; n < 2; ++n) acc[m][n] = (f32x4){0.f, 0.f, 0.f, 0.f};

        int row = tid >> 2, slot = tid & 3;
        int sp = slot ^ ((row >> 1) & 3);
        const char* pAh = (const char*)(DTh + (size_t)(ti + row) * N + sp * 8);
        const char* pAl = (const char*)(DTl + (size_t)(ti + row) * N + sp * 8);
        const char* pBh = (const char*)(Dh + (size_t)(tj + row) * N + sp * 8);
        const char* pBl = (const char*)(Dl + (size_t)(tj + row) * N + sp * 8);
        const int wb = wave * 1024;

        gload16(pAh, smem + 0     + wb);
        gload16(pAl, smem + 4096  + wb);
        gload16(pBh, smem + 8192  + wb);
        gload16(pBl, smem + 12288 + wb);
        __syncthreads();

        for (int t = 0; t < 16; ++t) {
            const char* base = smem + (t & 1) * 16384;
            s16x8 ah[2], al[2], bh[2], bl[2];
#pragma unroll
            for (int m = 0; m < 2; ++m) {
                int r2 = wm * 32 + m * 16 + rl;
                int off = r2 * 64 + (rh ^ ((r2 >> 1) & 3)) * 16;
                ah[m] = *reinterpret_cast<const s16x8*>(base + off);
                al[m] = *reinterpret_cast<const s16x8*>(base + 4096 + off);
            }
#pragma unroll
            for (int n = 0; n < 2; ++n) {
                int r2 = wn * 32 + n * 16 + rl;
                int off = r2 * 64 + (rh ^ ((r2 >> 1) & 3)) * 16;
                bh[n] = *reinterpret_cast<const s16x8*>(base + 8192 + off);
                bl[n] = *reinterpret_cast<const s16x8*>(base + 12288 + off);
            }
            if (t + 1 < 16) {
                const int kb = (t + 1) * 64;
                char* nb = smem + ((t + 1) & 1) * 16384;
                gload16(pAh + kb, nb + 0     + wb);
                gload16(pAl + kb, nb + 4096  + wb);
                gload16(pBh + kb, nb + 8192  + wb);
                gload16(pBl + kb, nb + 12288 + wb);
            }
#pragma unroll
            for (int m = 0; m < 2; ++m)
#pragma unroll
                for (int n = 0; n < 2; ++n) {
                    acc[m][n] = __builtin_amdgcn_mfma_f32_16x16x32_bf16(ah[m], bh[n], acc[m][n], 0, 0, 0);
                    acc[m][n] = __builtin_amdgcn_mfma_f32_16x16x32_bf16(ah[m], bl[n], acc[m][n], 0, 0, 0);
                    acc[m][n] = __builtin_amdgcn_mfma_f32_16x16x32_bf16(al[m], bh[n], acc[m][n], 0, 0, 0);
                }
            __syncthreads();
        }

#pragma unroll
        for (int m = 0; m < 2; ++m)
#pragma unroll
            for (int n = 0; n < 2; ++n)
#pragma unroll
                for (int q = 0; q < 4; ++q) {
                    int i = ti + wm * 32 + m * 16 + rh * 4 + q;
                    int j = tj + wn * 32 + n * 16 + rl;
                    size_t off = (size_t)i * N + j;
                    float v = acc[m][n][q] + 2.0f * DTf[off];   // (D^2)^T + 2 D^T
                    DTfn[off] = v;
                    ushort h, l;
                    split2(v, h, l);
                    *reinterpret_cast<ushort*>(DTnh + off) = h;
                    *reinterpret_cast<ushort*>(DTnl + off) = l;
                    size_t offT = (size_t)j * N + i;
                    *reinterpret_cast<ushort*>(Dnh + offT) = h;
                    *reinterpret_cast<ushort*>(Dnl + offT) = l;
                }
        return;
    }

    // ======== big path (rows rotated so GEMM blocks dispatch first) ========
    int bigbx = (MODE == 0) ? ((int)blockIdx.x - SQX) : (int)blockIdx.x;
    const int sb = (MODE == 0) ? (shift >> 7) : 0;
    int rowBlk = bigbx + sb;
    bool isCopy = false;
    if (MODE == 0 && rowBlk >= (L / 128)) { rowBlk -= (L / 128); isCopy = true; }
    const long brow = (long)rowBlk * 128;
    const int bcol = blockIdx.y * 128;

    if (MODE == 0 && isCopy) {
        // rows fully below shift: Xo = Xi (pair copy)
#pragma unroll
        for (int j = 0; j < 8; ++j) {
            int c = j * 256 + tid;
            long off = (brow + (c >> 4)) * N + bcol + (c & 15) * 8;
            *reinterpret_cast<int4*>(Xoh + off) = *reinterpret_cast<const int4*>(Xih + off);
            *reinterpret_cast<int4*>(Xol + off) = *reinterpret_cast<const int4*>(Xil + off);
        }
        return;
    }

    f32x4 acc[4][4];
#pragma unroll
    for (int m = 0; m < 4; ++m)
#pragma unroll
        for (int n = 0; n < 4; ++n) acc[m][n] = (f32x4){0.f, 0.f, 0.f, 0.f};

    // staging pointers: chunk idx = q*256+tid; row=idx>>2, slot=idx&3,
    // pre-swizzled source slot' = slot ^ ((row>>1)&3); LDS linear dest.
    const char* pAh[2]; const char* pAl[2]; const char* pBh[2]; const char* pBl[2];
    int wb[2];
#pragma unroll
    for (int q = 0; q < 2; ++q) {
        int idx = q * 256 + tid;
        int row = idx >> 2, slot = idx & 3;
        int sp = slot ^ ((row >> 1) & 3);
        long gra = brow + row - (MODE == 0 ? (long)shift : 0);
        pAh[q] = (gra >= 0) ? (const char*)(Xih + gra * N + sp * 8) : (const char*)(zb + sp * 8);
        if (NM == 3)
            pAl[q] = (gra >= 0) ? (const char*)(Xil + gra * N + sp * 8) : (const char*)(zb + sp * 8);
        long eb = (long)(bcol + row) * N + sp * 8;
        pBh[q] = (const char*)(Dh + eb);
        if (NM == 3) pBl[q] = (const char*)(Dl + eb);
        wb[q] = (q * 256 + wave * 64) * 16;
    }

    // prologue: stage tile 0 into buf 0
#pragma unroll
    for (int q = 0; q < 2; ++q) {
        gload16(pAh[q], smem + 0 + wb[q]);
        if (NM == 3) gload16(pAl[q], smem + 8192 + wb[q]);
        gload16(pBh[q], smem + BO + wb[q]);
        if (NM == 3) gload16(pBl[q], smem + BO + 8192 + wb[q]);
    }
    __syncthreads();

    for (int t = 0; t < 16; ++t) {
        const char* base = smem + (t & 1) * LB;
        s16x8 ah[4], al[4], bh[4], bl[4];
#pragma unroll
        for (int m = 0; m < 4; ++m) {
            int row = wm * 64 + m * 16 + rl;
            int off = row * 64 + (rh ^ ((row >> 1) & 3)) * 16;
            ah[m] = *reinterpret_cast<const s16x8*>(base + off);
            if (NM == 3) al[m] = *reinterpret_cast<const s16x8*>(base + 8192 + off);
        }
#pragma unroll
        for (int n = 0; n < 4; ++n) {
            int row = wn * 64 + n * 16 + rl;
            int off = row * 64 + (rh ^ ((row >> 1) & 3)) * 16;
            bh[n] = *reinterpret_cast<const s16x8*>(base + BO + off);
            if (NM == 3) bl[n] = *reinterpret_cast<const s16x8*>(base + BO + 8192 + off);
        }
        // stage next tile into the other buffer (hides under MFMA below)
        if (t + 1 < 16) {
            const int kb = (t + 1) * 64;  // 32 cols * 2B
            char* nb = smem + ((t + 1) & 1) * LB;
#pragma unroll
            for (int q = 0; q < 2; ++q) {
                gload16(pAh[q] + kb, nb + 0 + wb[q]);
                if (NM == 3) gload16(pAl[q] + kb, nb + 8192 + wb[q]);
                gload16(pBh[q] + kb, nb + BO + wb[q]);
                if (NM == 3) gload16(pBl[q] + kb, nb + BO + 8192 + wb[q]);
            }
        }
#pragma unroll
        for (int m = 0; m < 4; ++m)
#pragma unroll
            for (int n = 0; n < 4; ++n) {
                acc[m][n] = __builtin_amdgcn_mfma_f32_16x16x32_bf16(ah[m], bh[n], acc[m][n], 0, 0, 0);
                if (NM == 3) {
                    acc[m][n] = __builtin_amdgcn_mfma_f32_16x16x32_bf16(ah[m], bl[n], acc[m][n], 0, 0, 0);
                    acc[m][n] = __builtin_amdgcn_mfma_f32_16x16x32_bf16(al[m], bh[n], acc[m][n], 0, 0, 0);
                }
            }
        __syncthreads();
    }

    // epilogue: C/D layout col=lane&15, row=(lane>>4)*4+reg  [m89/m91]
    const long orow0 = brow + wm * 64;
    const int ocol0 = bcol + wn * 64;
#pragma unroll
    for (int m = 0; m < 4; ++m) {
#pragma unroll
        for (int q = 0; q < 4; ++q) {
            long gi = orow0 + m * 16 + rh * 4 + q;
            long base = gi * N + ocol0 + rl;
            if (MODE == 0) {
                bool hasS = (gi >= (long)shift);
                long base2 = base - (long)shift * N;
#pragma unroll
                for (int n = 0; n < 4; ++n) {
                    long off = base + n * 16;
                    float v = acc[m][n][q] + b2f(Xih[off]) + b2f(Xil[off]);
                    if (hasS) {
                        long o2 = base2 + n * 16;
                        v += b2f(Xih[o2]) + b2f(Xil[o2]);
                    }
                    ushort h, l;
                    split2(v, h, l);
                    *reinterpret_cast<ushort*>(Xoh + off) = h;
                    *reinterpret_cast<ushort*>(Xol + off) = l;
                }
            } else {
#pragma unroll
                for (int n = 0; n < 4; ++n) {
                    long off = base + n * 16;
                    if (OUTF32) {
                        Of[off] = acc[m][n][q];
                    } else {
                        ushort h, l;
                        split2(acc[m][n][q], h, l);
                        *reinterpret_cast<ushort*>(Xoh + off) = h;
                        *reinterpret_cast<ushort*>(Xol + off) = l;
                    }
                }
            }
        }
    }
}

// ---------------- launcher ----------------

extern "C" void kernel_launch(void* const* d_in, const int* in_sizes, int n_in,
                              void* d_out, int out_size, void* d_ws, size_t ws_size,
                              hipStream_t stream) {
    (void)in_sizes; (void)n_in; (void)out_size; (void)ws_size;
    const float* A = (const float*)d_in[0];
    const float* B = (const float*)d_in[1];
    const float* C = (const float*)d_in[2];
    const float* u = (const float*)d_in[3];

    const size_t NN = (size_t)N * N;
    const size_t LN = (size_t)L * N;

    // X1 pair lives in d_out (2 x 16MB bf16 == 32MB f32 out buffer)
    bf16* X1h = (bf16*)d_out;
    bf16* X1l = X1h + LN;

    char* w = (char*)d_ws;
    bf16* X0h = (bf16*)w;      w += LN * 2;
    bf16* X0l = (bf16*)w;      w += LN * 2;
    bf16 *Dh_[2], *Dl_[2], *DTh_[2], *DTl_[2];
    float* DTf_[2];
    for (int s = 0; s < 2; ++s) {
        Dh_[s]  = (bf16*)w;    w += NN * 2;
        Dl_[s]  = (bf16*)w;    w += NN * 2;
        DTh_[s] = (bf16*)w;    w += NN * 2;
        DTl_[s] = (bf16*)w;    w += NN * 2;
        DTf_[s] = (float*)w;   w += NN * 4;
    }
    float* M   = (float*)w;    w += NN * 4;
    float* MT  = (float*)w;    w += NN * 4;
    float* M2  = (float*)w;    w += NN * 4;
    float* BLm = (float*)w;    w += NN * 4;
    float* BT  = (float*)w;    w += NN * 4;
    float* Bbf = (float*)w;    w += NN * 4;
    float* D0f = (float*)w;    w += NN * 4;
    bf16* Bbh  = (bf16*)w;     w += NN * 2;
    bf16* Bbl  = (bf16*)w;     w += NN * 2;
    bf16* Ch   = (bf16*)w;     w += NN * 2;
    bf16* Cl   = (bf16*)w;     w += NN * 2;
    bf16* zb   = (bf16*)w;     w += 2048;

    const float step = 1.0f / (float)L;

    dim3 b256(256);
    dim3 gEl((int)((NN + 255) / 256));
    dim3 bT(32, 8), gT(N / 32, N / 32);
    dim3 g64(N / 64, N / 64);
    dim3 gBig(L / 128, N / 128);
    dim3 gRound(SQX + L / 128, N / 128);   // sq blocks first, then 128 big rows
    dim3 gS4n((int)(NN / 4 / 256));
    dim3 gS4L((int)(LN / 4 / 256));

    k_zeroinit<<<2, 256, 0, stream>>>((int*)zb);

    // ---- setup ----
    k_scale<<<gEl, b256, 0, stream>>>(A, M, step * 0.5f, (int)NN);
    k_transpose<<<gT, bT, 0, stream>>>(M, MT);
    k_qsq<<<g64, b256, 0, stream>>>(M, MT, M2, Bbh, Bbl, 1.0f);             // M2 = M@M (splits scratch)
    k_buildD<<<gEl, b256, 0, stream>>>(M, M2, D0f, Dh_[0], Dl_[0], BLm);    // D_0, BL
    k_tsplit<<<gT, bT, 0, stream>>>(D0f, DTf_[0], DTh_[0], DTl_[0]);        // D_0^T
    k_transpose<<<gT, bT, 0, stream>>>(B, BT);
    k_qsq<<<g64, b256, 0, stream>>>(BLm, BT, Bbf, Bbh, Bbl, step);          // Bb (+ split)
    k_split4<<<gS4n, b256, 0, stream>>>(C, Ch, Cl, (int)(NN / 4));
    k_split4<<<gS4L, b256, 0, stream>>>(u, X1h, X1l, (int)(LN / 4));        // u pair -> X1

    // ---- Bu = u @ Bb^T -> X0 pair ----
    k_round<3, 1, false><<<gBig, b256, 0, stream>>>(
        X1h, X1l, X0h, X0l, nullptr, Bbh, Bbl,
        nullptr, nullptr, nullptr, nullptr, nullptr, nullptr, nullptr, nullptr, 0, 0, zb);

    // ---- 14 doubling rounds (D_{r+1} squaring fused, sq first, copies last) ----
    for (int r = 0; r < 14; ++r) {
        int s = r & 1, nx = s ^ 1;
        bf16* Xih = (r & 1) ? X1h : X0h;  bf16* Xil = (r & 1) ? X1l : X0l;
        bf16* Xoh = (r & 1) ? X0h : X1h;  bf16* Xol = (r & 1) ? X0l : X1l;
        int doSq = (r < 13) ? 1 : 0;
        if (r < 10)
            k_round<1, 0, false><<<gRound, b256, 0, stream>>>(
                Xih, Xil, Xoh, Xol, nullptr, Dh_[s], Dl_[s],
                DTh_[s], DTl_[s], DTf_[s],
                Dh_[nx], Dl_[nx], DTh_[nx], DTl_[nx], DTf_[nx], 1 << r, doSq, zb);
        else
            k_round<3, 0, false><<<gRound, b256, 0, stream>>>(
                Xih, Xil, Xoh, Xol, nullptr, Dh_[s], Dl_[s],
                DTh_[s], DTl_[s], DTf_[s],
                Dh_[nx], Dl_[nx], DTh_[nx], DTl_[nx], DTf_[nx], 1 << r, doSq, zb);
    }

    // ---- final: OUT = X0 @ C^T (f32, overwrites d_out; X1 no longer needed) ----
    k_round<3, 1, true><<<gBig, b256, 0, stream>>>(
        X0h, X0l, nullptr, nullptr, (float*)d_out, Ch, Cl,
        nullptr, nullptr, nullptr, nullptr, nullptr, nullptr, nullptr, nullptr, 0, 0, zb);
}

// Round 9
// 500.642 us; speedup vs baseline: 2.7058x; 1.6071x over previous
//
#include <hip/hip_runtime.h>
#include <hip/hip_bf16.h>

static constexpr int N = 512;    // state size == feature size
static constexpr int L = 16384;  // sequence length
static constexpr int SQX = 16;   // sq blocks occupy bx < SQX in k_drnd

typedef short s16x8 __attribute__((ext_vector_type(8)));
typedef float f32x4 __attribute__((ext_vector_type(4)));
using bf16 = __hip_bfloat16;

#define GPTR(p) ((const __attribute__((address_space(1))) void*)(p))
#define LPTR(p) ((__attribute__((address_space(3))) void*)(p))
__device__ __forceinline__ void gload16(const void* g, void* l) {
    __builtin_amdgcn_global_load_lds(GPTR(g), LPTR(l), 16, 0, 0);
}

__device__ __forceinline__ void split2(float v, ushort& h, ushort& l) {
    bf16 hb = __float2bfloat16(v);
    h = *reinterpret_cast<ushort*>(&hb);
    bf16 lb = __float2bfloat16(v - __bfloat162float(hb));
    l = *reinterpret_cast<ushort*>(&lb);
}
__device__ __forceinline__ float b2f(bf16 x) { return __bfloat162float(x); }
__device__ __forceinline__ float us2f(ushort u) {
    return __bfloat162float(*reinterpret_cast<bf16*>(&u));
}

// ---------------- small setup kernels ----------------

__global__ void k_zeroinit(int* zb) { zb[blockIdx.x * 256 + threadIdx.x] = 0; }

__global__ void k_scale(const float* __restrict__ A, float* __restrict__ M, float h, int n) {
    int i = blockIdx.x * 256 + threadIdx.x;
    if (i < n) M[i] = A[i] * h;
}

// D0 = 2(M+M^2) (f32 + split), BL = I + M + M^2
__global__ void k_buildD(const float* __restrict__ M, const float* __restrict__ M2,
                         float* __restrict__ D0f, bf16* __restrict__ Dh,
                         bf16* __restrict__ Dl, float* __restrict__ BLm) {
    int i = blockIdx.x * 256 + threadIdx.x;
    if (i >= N * N) return;
    float m = M[i], m2 = M2[i];
    float d = 2.0f * (m + m2);
    D0f[i] = d;
    ushort h, l;
    split2(d, h, l);
    *reinterpret_cast<ushort*>(Dh + i) = h;
    *reinterpret_cast<ushort*>(Dl + i) = l;
    BLm[i] = (((i >> 9) == (i & (N - 1))) ? 1.0f : 0.0f) + m + m2;
}

// vectorized f32 -> (hi, lo) bf16 split, 4 elems/thread
__global__ void k_split4(const float* __restrict__ in, bf16* __restrict__ hi,
                         bf16* __restrict__ lo, int n4) {
    int i = blockIdx.x * 256 + threadIdx.x;
    if (i >= n4) return;
    float4 v = reinterpret_cast<const float4*>(in)[i];
    ushort ht[4], lt[4];
    split2(v.x, ht[0], lt[0]);
    split2(v.y, ht[1], lt[1]);
    split2(v.z, ht[2], lt[2]);
    split2(v.w, ht[3], lt[3]);
    *reinterpret_cast<ushort4*>(hi + 4 * (size_t)i) = *reinterpret_cast<ushort4*>(ht);
    *reinterpret_cast<ushort4*>(lo + 4 * (size_t)i) = *reinterpret_cast<ushort4*>(lt);
}

// 512x512 f32 transpose
__global__ void k_transpose(const float* __restrict__ in, float* __restrict__ out) {
    __shared__ float t[32][33];
    int bx = blockIdx.x * 32, by = blockIdx.y * 32;
    int tx = threadIdx.x, ty = threadIdx.y;  // block 32x8
#pragma unroll
    for (int j = 0; j < 32; j += 8) t[ty + j][tx] = in[(by + ty + j) * N + bx + tx];
    __syncthreads();
#pragma unroll
    for (int j = 0; j < 32; j += 8) out[(bx + ty + j) * N + by + tx] = t[tx][ty + j];
}

// transpose + f32 master + bf16 split of the transpose
__global__ void k_tsplit(const float* __restrict__ in, float* __restrict__ of,
                         bf16* __restrict__ oh, bf16* __restrict__ ol) {
    __shared__ float t[32][33];
    int bx = blockIdx.x * 32, by = blockIdx.y * 32;
    int tx = threadIdx.x, ty = threadIdx.y;
#pragma unroll
    for (int j = 0; j < 32; j += 8) t[ty + j][tx] = in[(by + ty + j) * N + bx + tx];
    __syncthreads();
#pragma unroll
    for (int j = 0; j < 32; j += 8) {
        float v = t[tx][ty + j];
        size_t off = (size_t)(bx + ty + j) * N + by + tx;
        of[off] = v;
        ushort h, l;
        split2(v, h, l);
        *reinterpret_cast<ushort*>(oh + off) = h;
        *reinterpret_cast<ushort*>(ol + off) = l;
    }
}

// ---------------- f32 NT GEMM 64x64 + fused bf16-split epilogue (setup only) ----
__global__ __launch_bounds__(256) void k_qsq(
    const float* __restrict__ Asrc, const float* __restrict__ Bmat,
    float* __restrict__ OUT, bf16* __restrict__ Sh, bf16* __restrict__ Sl, float scale) {
    __shared__ float As[32][64];
    __shared__ float Bs[32][64];
    const int tid = threadIdx.x;
    const int brow = blockIdx.x * 64;
    const int bcol = blockIdx.y * 64;
    const int tx = tid & 15, ty = tid >> 4;
    float acc[4][4] = {};

    for (int k0 = 0; k0 < N; k0 += 32) {
#pragma unroll
        for (int q = 0; q < 2; ++q) {
            int idx = tid * 2 + q;
            int row = idx >> 3;
            int kq = (idx & 7) << 2;
            float4 va = *(const float4*)(Asrc + (long)(brow + row) * N + k0 + kq);
            As[kq + 0][row] = va.x; As[kq + 1][row] = va.y;
            As[kq + 2][row] = va.z; As[kq + 3][row] = va.w;
            float4 vb = *(const float4*)(Bmat + (long)(bcol + row) * N + k0 + kq);
            Bs[kq + 0][row] = vb.x; Bs[kq + 1][row] = vb.y;
            Bs[kq + 2][row] = vb.z; Bs[kq + 3][row] = vb.w;
        }
        __syncthreads();
#pragma unroll
        for (int kk = 0; kk < 32; ++kk) {
            float a[4], b[4];
            *(float4*)&a[0] = *(const float4*)&As[kk][ty * 4];
            *(float4*)&b[0] = *(const float4*)&Bs[kk][tx * 4];
#pragma unroll
            for (int i = 0; i < 4; ++i)
#pragma unroll
                for (int j = 0; j < 4; ++j) acc[i][j] = fmaf(a[i], b[j], acc[i][j]);
        }
        __syncthreads();
    }
#pragma unroll
    for (int i = 0; i < 4; ++i) {
        long off = (long)(brow + ty * 4 + i) * N + bcol + tx * 4;
        float4 o = make_float4(acc[i][0] * scale, acc[i][1] * scale,
                               acc[i][2] * scale, acc[i][3] * scale);
        *(float4*)(OUT + off) = o;
        ushort ht[4], lt[4];
        split2(o.x, ht[0], lt[0]); split2(o.y, ht[1], lt[1]);
        split2(o.z, ht[2], lt[2]); split2(o.w, ht[3], lt[3]);
        *reinterpret_cast<ushort4*>(Sh + off) = *reinterpret_cast<ushort4*>(ht);
        *reinterpret_cast<ushort4*>(Sl + off) = *reinterpret_cast<ushort4*>(lt);
    }
}

// ---------------- k_plain: round-3 verified bf16x3 128x128 GEMM --------------
// OUT = A @ B^T; A,B bf16 (hi,lo) pairs; out = bf16 pair or f32.
template <bool OUTF32>
__global__ __launch_bounds__(256, 2) void k_plain(
    const bf16* __restrict__ Ah, const bf16* __restrict__ Al,
    const bf16* __restrict__ Bh, const bf16* __restrict__ Bl,
    bf16* __restrict__ Oh, bf16* __restrict__ Ol, float* __restrict__ Of)
{
    __shared__ char smem[65536];
    const int tid = threadIdx.x;
    const int wave = tid >> 6, lane = tid & 63;
    const long brow = (long)blockIdx.x * 128;
    const int bcol = blockIdx.y * 128;
    const int wm = wave >> 1, wn = wave & 1;

    f32x4 acc[4][4];
#pragma unroll
    for (int m = 0; m < 4; ++m)
#pragma unroll
        for (int n = 0; n < 4; ++n) acc[m][n] = (f32x4){0.f, 0.f, 0.f, 0.f};

    const char* pAh[2]; const char* pAl[2]; const char* pBh[2]; const char* pBl[2];
    int wb[2];
#pragma unroll
    for (int q = 0; q < 2; ++q) {
        int idx = q * 256 + tid;
        int row = idx >> 2, slot = idx & 3;
        int sp = slot ^ ((row >> 1) & 3);
        pAh[q] = (const char*)(Ah + (brow + row) * N + sp * 8);
        pAl[q] = (const char*)(Al + (brow + row) * N + sp * 8);
        long eb = (long)(bcol + row) * N + sp * 8;
        pBh[q] = (const char*)(Bh + eb);
        pBl[q] = (const char*)(Bl + eb);
        wb[q] = (q * 256 + wave * 64) * 16;
    }
    const int slot = lane >> 4;
    const int rl = lane & 15;

#pragma unroll
    for (int q = 0; q < 2; ++q) {
        gload16(pAh[q], smem + 0     + wb[q]);
        gload16(pAl[q], smem + 8192  + wb[q]);
        gload16(pBh[q], smem + 16384 + wb[q]);
        gload16(pBl[q], smem + 24576 + wb[q]);
    }
    __syncthreads();

    for (int t = 0; t < 16; ++t) {
        const char* base = smem + (t & 1) * 32768;
        s16x8 ah[4], al[4], bh[4], bl[4];
#pragma unroll
        for (int m = 0; m < 4; ++m) {
            int row = wm * 64 + m * 16 + rl;
            int off = row * 64 + (slot ^ ((row >> 1) & 3)) * 16;
            ah[m] = *reinterpret_cast<const s16x8*>(base + off);
            al[m] = *reinterpret_cast<const s16x8*>(base + 8192 + off);
        }
#pragma unroll
        for (int n = 0; n < 4; ++n) {
            int row = wn * 64 + n * 16 + rl;
            int off = row * 64 + (slot ^ ((row >> 1) & 3)) * 16;
            bh[n] = *reinterpret_cast<const s16x8*>(base + 16384 + off);
            bl[n] = *reinterpret_cast<const s16x8*>(base + 24576 + off);
        }
        if (t + 1 < 16) {
            const int kb = (t + 1) * 64;
            char* nb = smem + ((t + 1) & 1) * 32768;
#pragma unroll
            for (int q = 0; q < 2; ++q) {
                gload16(pAh[q] + kb, nb + 0     + wb[q]);
                gload16(pAl[q] + kb, nb + 8192  + wb[q]);
                gload16(pBh[q] + kb, nb + 16384 + wb[q]);
                gload16(pBl[q] + kb, nb + 24576 + wb[q]);
            }
        }
#pragma unroll
        for (int m = 0; m < 4; ++m)
#pragma unroll
            for (int n = 0; n < 4; ++n) {
                acc[m][n] = __builtin_amdgcn_mfma_f32_16x16x32_bf16(ah[m], bh[n], acc[m][n], 0, 0, 0);
                acc[m][n] = __builtin_amdgcn_mfma_f32_16x16x32_bf16(ah[m], bl[n], acc[m][n], 0, 0, 0);
                acc[m][n] = __builtin_amdgcn_mfma_f32_16x16x32_bf16(al[m], bh[n], acc[m][n], 0, 0, 0);
            }
        __syncthreads();
    }

    const int rh = lane >> 4;
    const long orow0 = brow + wm * 64;
    const int ocol0 = bcol + wn * 64;
#pragma unroll
    for (int m = 0; m < 4; ++m) {
#pragma unroll
        for (int q = 0; q < 4; ++q) {
            long row = orow0 + m * 16 + rh * 4 + q;
            long base = row * N + ocol0 + rl;
#pragma unroll
            for (int n = 0; n < 4; ++n) {
                float v = acc[m][n][q];
                long off = base + n * 16;
                if (OUTF32) {
                    Of[off] = v;
                } else {
                    ushort h, l;
                    split2(v, h, l);
                    *reinterpret_cast<ushort*>(Oh + off) = h;
                    *reinterpret_cast<ushort*>(Ol + off) = l;
                }
            }
        }
    }
}

// ---------------- k_drnd: D-form doubling round, NM=1, vector epilogue --------
// bx < SQX: sq blocks: Dnext = D^2 + 2D (bf16x3, both orientations + f32 DT).
// else: Xo[i] = Xi[i] + Xi[i-s] + (Xi[i-s] @ D^T)[i]  (single-MFMA product term);
//   big rows rotated by shift/128 so copy rows dispatch last as pure pair-copies.
__global__ __launch_bounds__(256, 3) void k_drnd(
    const bf16* __restrict__ Xih, const bf16* __restrict__ Xil,
    bf16* __restrict__ Xoh, bf16* __restrict__ Xol,
    const bf16* __restrict__ Dh, const bf16* __restrict__ Dl,
    const bf16* __restrict__ DTh, const bf16* __restrict__ DTl,
    const float* __restrict__ DTf,
    bf16* __restrict__ Dnh, bf16* __restrict__ Dnl,
    bf16* __restrict__ DTnh, bf16* __restrict__ DTnl, float* __restrict__ DTfn,
    int shift, int doSq, const bf16* __restrict__ zb)
{
    __shared__ char smem[32768];
    const int tid = threadIdx.x;
    const int wave = tid >> 6, lane = tid & 63;
    const int wm = wave >> 1, wn = wave & 1;
    const int rl = lane & 15, rh = lane >> 4;

    if (blockIdx.x < SQX) {
        // ======== D-squaring path (64 blocks, dispatched first, bf16x3) ========
        if (!doSq) return;
        int sidx = (int)blockIdx.x * (int)gridDim.y + (int)blockIdx.y;  // 0..63
        const int ti = (sidx >> 3) * 64, tj = (sidx & 7) * 64;

        f32x4 acc[2][2];
#pragma unroll
        for (int m = 0; m < 2; ++m)
#pragma unroll
            for (int n = 0; n < 2; ++n) acc[m][n] = (f32x4){0.f, 0.f, 0.f, 0.f};

        int row = tid >> 2, slot = tid & 3;
        int sp = slot ^ ((row >> 1) & 3);
        const char* pAh = (const char*)(DTh + (size_t)(ti + row) * N + sp * 8);
        const char* pAl = (const char*)(DTl + (size_t)(ti + row) * N + sp * 8);
        const char* pBh = (const char*)(Dh + (size_t)(tj + row) * N + sp * 8);
        const char* pBl = (const char*)(Dl + (size_t)(tj + row) * N + sp * 8);
        const int wb = wave * 1024;

        gload16(pAh, smem + 0     + wb);
        gload16(pAl, smem + 4096  + wb);
        gload16(pBh, smem + 8192  + wb);
        gload16(pBl, smem + 12288 + wb);
        __syncthreads();

        for (int t = 0; t < 16; ++t) {
            const char* base = smem + (t & 1) * 16384;
            s16x8 ah[2], al[2], bh[2], bl[2];
#pragma unroll
            for (int m = 0; m < 2; ++m) {
                int r2 = wm * 32 + m * 16 + rl;
                int off = r2 * 64 + (rh ^ ((r2 >> 1) & 3)) * 16;
                ah[m] = *reinterpret_cast<const s16x8*>(base + off);
                al[m] = *reinterpret_cast<const s16x8*>(base + 4096 + off);
            }
#pragma unroll
            for (int n = 0; n < 2; ++n) {
                int r2 = wn * 32 + n * 16 + rl;
                int off = r2 * 64 + (rh ^ ((r2 >> 1) & 3)) * 16;
                bh[n] = *reinterpret_cast<const s16x8*>(base + 8192 + off);
                bl[n] = *reinterpret_cast<const s16x8*>(base + 12288 + off);
            }
            if (t + 1 < 16) {
                const int kb = (t + 1) * 64;
                char* nb = smem + ((t + 1) & 1) * 16384;
                gload16(pAh + kb, nb + 0     + wb);
                gload16(pAl + kb, nb + 4096  + wb);
                gload16(pBh + kb, nb + 8192  + wb);
                gload16(pBl + kb, nb + 12288 + wb);
            }
#pragma unroll
            for (int m = 0; m < 2; ++m)
#pragma unroll
                for (int n = 0; n < 2; ++n) {
                    acc[m][n] = __builtin_amdgcn_mfma_f32_16x16x32_bf16(ah[m], bh[n], acc[m][n], 0, 0, 0);
                    acc[m][n] = __builtin_amdgcn_mfma_f32_16x16x32_bf16(ah[m], bl[n], acc[m][n], 0, 0, 0);
                    acc[m][n] = __builtin_amdgcn_mfma_f32_16x16x32_bf16(al[m], bh[n], acc[m][n], 0, 0, 0);
                }
            __syncthreads();
        }

#pragma unroll
        for (int m = 0; m < 2; ++m)
#pragma unroll
            for (int n = 0; n < 2; ++n)
#pragma unroll
                for (int q = 0; q < 4; ++q) {
                    int i = ti + wm * 32 + m * 16 + rh * 4 + q;
                    int j = tj + wn * 32 + n * 16 + rl;
                    size_t off = (size_t)i * N + j;
                    float v = acc[m][n][q] + 2.0f * DTf[off];   // (D^2)^T + 2 D^T
                    DTfn[off] = v;
                    ushort h, l;
                    split2(v, h, l);
                    *reinterpret_cast<ushort*>(DTnh + off) = h;
                    *reinterpret_cast<ushort*>(DTnl + off) = l;
                    size_t offT = (size_t)j * N + i;
                    *reinterpret_cast<ushort*>(Dnh + offT) = h;
                    *reinterpret_cast<ushort*>(Dnl + offT) = l;
                }
        return;
    }

    // ======== big path (rows rotated so GEMM blocks dispatch first) ========
    int bigbx = (int)blockIdx.x - SQX;
    const int sb = shift >> 7;
    int rowBlk = bigbx + sb;
    bool isCopy = false;
    if (rowBlk >= (L / 128)) { rowBlk -= (L / 128); isCopy = true; }
    const long brow = (long)rowBlk * 128;
    const int bcol = blockIdx.y * 128;

    if (isCopy) {
#pragma unroll
        for (int j = 0; j < 8; ++j) {
            int c = j * 256 + tid;
            long off = (brow + (c >> 4)) * N + bcol + (c & 15) * 8;
            *reinterpret_cast<int4*>(Xoh + off) = *reinterpret_cast<const int4*>(Xih + off);
            *reinterpret_cast<int4*>(Xol + off) = *reinterpret_cast<const int4*>(Xil + off);
        }
        return;
    }

    f32x4 acc[4][4];
#pragma unroll
    for (int m = 0; m < 4; ++m)
#pragma unroll
        for (int n = 0; n < 4; ++n) acc[m][n] = (f32x4){0.f, 0.f, 0.f, 0.f};

    // staging: A = X_hi[i-shift] (zb redirect for rows < 0), B = D_hi
    const char* pA[2]; const char* pB[2]; int wb[2];
#pragma unroll
    for (int q = 0; q < 2; ++q) {
        int idx = q * 256 + tid;
        int row = idx >> 2, slot = idx & 3;
        int sp = slot ^ ((row >> 1) & 3);
        long gra = brow + row - (long)shift;
        pA[q] = (gra >= 0) ? (const char*)(Xih + gra * N + sp * 8)
                           : (const char*)(zb + sp * 8);
        pB[q] = (const char*)(Dh + (long)(bcol + row) * N + sp * 8);
        wb[q] = (q * 256 + wave * 64) * 16;
    }

    // prologue
#pragma unroll
    for (int q = 0; q < 2; ++q) {
        gload16(pA[q], smem + 0    + wb[q]);
        gload16(pB[q], smem + 8192 + wb[q]);
    }
    __syncthreads();

    for (int t = 0; t < 16; ++t) {
        const char* base = smem + (t & 1) * 16384;
        s16x8 a[4], b[4];
#pragma unroll
        for (int m = 0; m < 4; ++m) {
            int row = wm * 64 + m * 16 + rl;
            a[m] = *reinterpret_cast<const s16x8*>(base + row * 64 + (rh ^ ((row >> 1) & 3)) * 16);
        }
#pragma unroll
        for (int n = 0; n < 4; ++n) {
            int row = wn * 64 + n * 16 + rl;
            b[n] = *reinterpret_cast<const s16x8*>(base + 8192 + row * 64 + (rh ^ ((row >> 1) & 3)) * 16);
        }
        if (t + 1 < 16) {
            const int kb = (t + 1) * 64;
            char* nb = smem + ((t + 1) & 1) * 16384;
#pragma unroll
            for (int q = 0; q < 2; ++q) {
                gload16(pA[q] + kb, nb + 0    + wb[q]);
                gload16(pB[q] + kb, nb + 8192 + wb[q]);
            }
        }
#pragma unroll
        for (int m = 0; m < 4; ++m)
#pragma unroll
            for (int n = 0; n < 4; ++n)
                acc[m][n] = __builtin_amdgcn_mfma_f32_16x16x32_bf16(a[m], b[n], acc[m][n], 0, 0, 0);
        __syncthreads();
    }

    // ---- vectorized epilogue via LDS retile (two 64-row halves, 32KB each) ----
    float* eld = (float*)smem;
    const int erow = tid >> 2;          // 0..63
    const int ec   = (tid & 3) * 8;     // cols ec + s*32, s=0..3
    for (int h = 0; h < 2; ++h) {
        if (wm == h) {
#pragma unroll
            for (int m = 0; m < 4; ++m)
#pragma unroll
                for (int q = 0; q < 4; ++q) {
                    int br = m * 16 + rh * 4 + q;        // 0..63
                    int sw = (br & 7) << 2;
#pragma unroll
                    for (int n = 0; n < 4; ++n) {
                        int col = wn * 64 + n * 16 + rl;
                        eld[br * 128 + (col ^ sw)] = acc[m][n][q];
                    }
                }
        }
        __syncthreads();
        {
            long gi = brow + h * 64 + erow;
            bool hasS = gi >= (long)shift;
            const int sw = (erow & 7) << 2;
            long gb = gi * N + bcol;
            long gs = gb - (long)shift * N;
#pragma unroll
            for (int s = 0; s < 4; ++s) {
                int c = ec + s * 32;
                f32x4 v0 = *reinterpret_cast<const f32x4*>(&eld[erow * 128 + (c ^ sw)]);
                f32x4 v1 = *reinterpret_cast<const f32x4*>(&eld[erow * 128 + ((c ^ sw) ^ 4)]);
                float r[8];
                *reinterpret_cast<f32x4*>(&r[0]) = v0;
                *reinterpret_cast<f32x4*>(&r[4]) = v1;
                ushort vh[8], vl[8];
                *reinterpret_cast<int4*>(vh) = *reinterpret_cast<const int4*>(Xih + gb + c);
                *reinterpret_cast<int4*>(vl) = *reinterpret_cast<const int4*>(Xil + gb + c);
#pragma unroll
                for (int j = 0; j < 8; ++j) r[j] += us2f(vh[j]) + us2f(vl[j]);
                if (hasS) {
                    *reinterpret_cast<int4*>(vh) = *reinterpret_cast<const int4*>(Xih + gs + c);
                    *reinterpret_cast<int4*>(vl) = *reinterpret_cast<const int4*>(Xil + gs + c);
#pragma unroll
                    for (int j = 0; j < 8; ++j) r[j] += us2f(vh[j]) + us2f(vl[j]);
                }
                ushort oh[8], ol[8];
#pragma unroll
                for (int j = 0; j < 8; ++j) split2(r[j], oh[j], ol[j]);
                *reinterpret_cast<int4*>(Xoh + gb + c) = *reinterpret_cast<int4*>(oh);
                *reinterpret_cast<int4*>(Xol + gb + c) = *reinterpret_cast<int4*>(ol);
            }
        }
        __syncthreads();
    }
}

// ---------------- launcher ----------------

extern "C" void kernel_launch(void* const* d_in, const int* in_sizes, int n_in,
                              void* d_out, int out_size, void* d_ws, size_t ws_size,
                              hipStream_t stream) {
    (void)in_sizes; (void)n_in; (void)out_size; (void)ws_size;
    const float* A = (const float*)d_in[0];
    const float* B = (const float*)d_in[1];
    const float* C = (const float*)d_in[2];
    const float* u = (const float*)d_in[3];

    const size_t NN = (size_t)N * N;
    const size_t LN = (size_t)L * N;

    // X1 pair lives in d_out (2 x 16MB bf16 == 32MB f32 out buffer)
    bf16* X1h = (bf16*)d_out;
    bf16* X1l = X1h + LN;

    char* w = (char*)d_ws;
    bf16* X0h = (bf16*)w;      w += LN * 2;
    bf16* X0l = (bf16*)w;      w += LN * 2;
    bf16 *Dh_[2], *Dl_[2], *DTh_[2], *DTl_[2];
    float* DTf_[2];
    for (int s = 0; s < 2; ++s) {
        Dh_[s]  = (bf16*)w;    w += NN * 2;
        Dl_[s]  = (bf16*)w;    w += NN * 2;
        DTh_[s] = (bf16*)w;    w += NN * 2;
        DTl_[s] = (bf16*)w;    w += NN * 2;
        DTf_[s] = (float*)w;   w += NN * 4;
    }
    float* M   = (float*)w;    w += NN * 4;
    float* MT  = (float*)w;    w += NN * 4;
    float* M2  = (float*)w;    w += NN * 4;
    float* BLm = (float*)w;    w += NN * 4;
    float* BT  = (float*)w;    w += NN * 4;
    float* Bbf = (float*)w;    w += NN * 4;
    float* D0f = (float*)w;    w += NN * 4;
    bf16* Bbh  = (bf16*)w;     w += NN * 2;
    bf16* Bbl  = (bf16*)w;     w += NN * 2;
    bf16* Ch   = (bf16*)w;     w += NN * 2;
    bf16* Cl   = (bf16*)w;     w += NN * 2;
    bf16* zb   = (bf16*)w;     w += 2048;

    const float step = 1.0f / (float)L;

    dim3 b256(256);
    dim3 gEl((int)((NN + 255) / 256));
    dim3 bT(32, 8), gT(N / 32, N / 32);
    dim3 g64(N / 64, N / 64);
    dim3 gBig(L / 128, N / 128);
    dim3 gRound(SQX + L / 128, N / 128);   // sq blocks first, then 128 big rows
    dim3 gS4n((int)(NN / 4 / 256));
    dim3 gS4L((int)(LN / 4 / 256));

    k_zeroinit<<<2, 256, 0, stream>>>((int*)zb);

    // ---- setup ----
    k_scale<<<gEl, b256, 0, stream>>>(A, M, step * 0.5f, (int)NN);
    k_transpose<<<gT, bT, 0, stream>>>(M, MT);
    k_qsq<<<g64, b256, 0, stream>>>(M, MT, M2, Bbh, Bbl, 1.0f);             // M2 = M@M (splits scratch)
    k_buildD<<<gEl, b256, 0, stream>>>(M, M2, D0f, Dh_[0], Dl_[0], BLm);    // D_0, BL
    k_tsplit<<<gT, bT, 0, stream>>>(D0f, DTf_[0], DTh_[0], DTl_[0]);        // D_0^T
    k_transpose<<<gT, bT, 0, stream>>>(B, BT);
    k_qsq<<<g64, b256, 0, stream>>>(BLm, BT, Bbf, Bbh, Bbl, step);          // Bb (+ split)
    k_split4<<<gS4n, b256, 0, stream>>>(C, Ch, Cl, (int)(NN / 4));
    k_split4<<<gS4L, b256, 0, stream>>>(u, X1h, X1l, (int)(LN / 4));        // u pair -> X1

    // ---- Bu = u @ Bb^T -> X0 pair (bf16x3) ----
    k_plain<false><<<gBig, b256, 0, stream>>>(X1h, X1l, Bbh, Bbl, X0h, X0l, nullptr);

    // ---- 14 doubling rounds, all NM=1 D-form (sq fused, copies last) ----
    for (int r = 0; r < 14; ++r) {
        int s = r & 1, nx = s ^ 1;
        bf16* Xih = (r & 1) ? X1h : X0h;  bf16* Xil = (r & 1) ? X1l : X0l;
        bf16* Xoh = (r & 1) ? X0h : X1h;  bf16* Xol = (r & 1) ? X0l : X1l;
        int doSq = (r < 13) ? 1 : 0;
        k_drnd<<<gRound, b256, 0, stream>>>(
            Xih, Xil, Xoh, Xol, Dh_[s], Dl_[s],
            DTh_[s], DTl_[s], DTf_[s],
            Dh_[nx], Dl_[nx], DTh_[nx], DTl_[nx], DTf_[nx], 1 << r, doSq, zb);
    }

    // ---- final: OUT = X0 @ C^T (f32, overwrites d_out; X1 dead) ----
    k_plain<true><<<gBig, b256, 0, stream>>>(X0h, X0l, Ch, Cl, nullptr, nullptr, (float*)d_out);
}

// Round 10
// 473.006 us; speedup vs baseline: 2.8639x; 1.0584x over previous
//
#include <hip/hip_runtime.h>
#include <hip/hip_bf16.h>

static constexpr int N = 512;    // state size == feature size
static constexpr int L = 16384;  // sequence length
static constexpr int SQX = 16;   // sq blocks occupy bx < SQX in k_drnd

typedef short s16x8 __attribute__((ext_vector_type(8)));
typedef float f32x4 __attribute__((ext_vector_type(4)));
using bf16 = __hip_bfloat16;

#define GPTR(p) ((const __attribute__((address_space(1))) void*)(p))
#define LPTR(p) ((__attribute__((address_space(3))) void*)(p))
__device__ __forceinline__ void gload16(const void* g, void* l) {
    __builtin_amdgcn_global_load_lds(GPTR(g), LPTR(l), 16, 0, 0);
}

__device__ __forceinline__ void split2(float v, ushort& h, ushort& l) {
    bf16 hb = __float2bfloat16(v);
    h = *reinterpret_cast<ushort*>(&hb);
    bf16 lb = __float2bfloat16(v - __bfloat162float(hb));
    l = *reinterpret_cast<ushort*>(&lb);
}
__device__ __forceinline__ ushort f2h(float v) {
    bf16 hb = __float2bfloat16(v);
    return *reinterpret_cast<ushort*>(&hb);
}
__device__ __forceinline__ float us2f(ushort u) {
    return __bfloat162float(*reinterpret_cast<bf16*>(&u));
}

// ---------------- setup kernels ----------------

__global__ void k_zeroinit(int* zb) { zb[blockIdx.x * 256 + threadIdx.x] = 0; }

// M = A*h (straight) and MT = M^T in one pass
__global__ void k_prep(const float* __restrict__ A, float* __restrict__ M,
                       float* __restrict__ MT, float h) {
    __shared__ float t[32][33];
    int bx = blockIdx.x * 32, by = blockIdx.y * 32;
    int tx = threadIdx.x, ty = threadIdx.y;  // block 32x8
#pragma unroll
    for (int j = 0; j < 32; j += 8) {
        float v = A[(by + ty + j) * N + bx + tx] * h;
        t[ty + j][tx] = v;
        M[(by + ty + j) * N + bx + tx] = v;
    }
    __syncthreads();
#pragma unroll
    for (int j = 0; j < 32; j += 8) MT[(bx + ty + j) * N + by + tx] = t[tx][ty + j];
}

// D0 = 2(M+M^2): writes Dh/Dl straight, DTf/DTh/DTl transposed, BL straight
__global__ void k_buildDT(const float* __restrict__ M, const float* __restrict__ M2,
                          bf16* __restrict__ Dh, bf16* __restrict__ Dl,
                          float* __restrict__ DTf, bf16* __restrict__ DTh,
                          bf16* __restrict__ DTl, float* __restrict__ BLm) {
    __shared__ float t[32][33];
    int bx = blockIdx.x * 32, by = blockIdx.y * 32;
    int tx = threadIdx.x, ty = threadIdx.y;
#pragma unroll
    for (int j = 0; j < 32; j += 8) {
        int row = by + ty + j, col = bx + tx;
        size_t off = (size_t)row * N + col;
        float m = M[off], m2 = M2[off];
        float d = 2.0f * (m + m2);
        t[ty + j][tx] = d;
        ushort h, l;
        split2(d, h, l);
        *reinterpret_cast<ushort*>(Dh + off) = h;
        *reinterpret_cast<ushort*>(Dl + off) = l;
        BLm[off] = ((row == col) ? 1.0f : 0.0f) + m + m2;
    }
    __syncthreads();
#pragma unroll
    for (int j = 0; j < 32; j += 8) {
        float v = t[tx][ty + j];
        size_t off = (size_t)(bx + ty + j) * N + by + tx;
        DTf[off] = v;
        ushort h, l;
        split2(v, h, l);
        *reinterpret_cast<ushort*>(DTh + off) = h;
        *reinterpret_cast<ushort*>(DTl + off) = l;
    }
}

// vectorized f32 -> (hi, lo) bf16 split, 4 elems/thread
__global__ void k_split4(const float* __restrict__ in, bf16* __restrict__ hi,
                         bf16* __restrict__ lo, int n4) {
    int i = blockIdx.x * 256 + threadIdx.x;
    if (i >= n4) return;
    float4 v = reinterpret_cast<const float4*>(in)[i];
    ushort ht[4], lt[4];
    split2(v.x, ht[0], lt[0]);
    split2(v.y, ht[1], lt[1]);
    split2(v.z, ht[2], lt[2]);
    split2(v.w, ht[3], lt[3]);
    *reinterpret_cast<ushort4*>(hi + 4 * (size_t)i) = *reinterpret_cast<ushort4*>(ht);
    *reinterpret_cast<ushort4*>(lo + 4 * (size_t)i) = *reinterpret_cast<ushort4*>(lt);
}

// 512x512 f32 transpose
__global__ void k_transpose(const float* __restrict__ in, float* __restrict__ out) {
    __shared__ float t[32][33];
    int bx = blockIdx.x * 32, by = blockIdx.y * 32;
    int tx = threadIdx.x, ty = threadIdx.y;  // block 32x8
#pragma unroll
    for (int j = 0; j < 32; j += 8) t[ty + j][tx] = in[(by + ty + j) * N + bx + tx];
    __syncthreads();
#pragma unroll
    for (int j = 0; j < 32; j += 8) out[(bx + ty + j) * N + by + tx] = t[tx][ty + j];
}

// ---------------- f32 NT GEMM 64x64 + fused bf16-split epilogue (setup only) ----
__global__ __launch_bounds__(256) void k_qsq(
    const float* __restrict__ Asrc, const float* __restrict__ Bmat,
    float* __restrict__ OUT, bf16* __restrict__ Sh, bf16* __restrict__ Sl, float scale) {
    __shared__ float As[32][64];
    __shared__ float Bs[32][64];
    const int tid = threadIdx.x;
    const int brow = blockIdx.x * 64;
    const int bcol = blockIdx.y * 64;
    const int tx = tid & 15, ty = tid >> 4;
    float acc[4][4] = {};

    for (int k0 = 0; k0 < N; k0 += 32) {
#pragma unroll
        for (int q = 0; q < 2; ++q) {
            int idx = tid * 2 + q;
            int row = idx >> 3;
            int kq = (idx & 7) << 2;
            float4 va = *(const float4*)(Asrc + (long)(brow + row) * N + k0 + kq);
            As[kq + 0][row] = va.x; As[kq + 1][row] = va.y;
            As[kq + 2][row] = va.z; As[kq + 3][row] = va.w;
            float4 vb = *(const float4*)(Bmat + (long)(bcol + row) * N + k0 + kq);
            Bs[kq + 0][row] = vb.x; Bs[kq + 1][row] = vb.y;
            Bs[kq + 2][row] = vb.z; Bs[kq + 3][row] = vb.w;
        }
        __syncthreads();
#pragma unroll
        for (int kk = 0; kk < 32; ++kk) {
            float a[4], b[4];
            *(float4*)&a[0] = *(const float4*)&As[kk][ty * 4];
            *(float4*)&b[0] = *(const float4*)&Bs[kk][tx * 4];
#pragma unroll
            for (int i = 0; i < 4; ++i)
#pragma unroll
                for (int j = 0; j < 4; ++j) acc[i][j] = fmaf(a[i], b[j], acc[i][j]);
        }
        __syncthreads();
    }
#pragma unroll
    for (int i = 0; i < 4; ++i) {
        long off = (long)(brow + ty * 4 + i) * N + bcol + tx * 4;
        float4 o = make_float4(acc[i][0] * scale, acc[i][1] * scale,
                               acc[i][2] * scale, acc[i][3] * scale);
        *(float4*)(OUT + off) = o;
        ushort ht[4], lt[4];
        split2(o.x, ht[0], lt[0]); split2(o.y, ht[1], lt[1]);
        split2(o.z, ht[2], lt[2]); split2(o.w, ht[3], lt[3]);
        *reinterpret_cast<ushort4*>(Sh + off) = *reinterpret_cast<ushort4*>(ht);
        *reinterpret_cast<ushort4*>(Sl + off) = *reinterpret_cast<ushort4*>(lt);
    }
}

// ---------------- k_bu: X0 = u @ Bb^T, NM=1 (hi*hi), u reg-staged from f32 -----
// A: u f32, loaded to regs, converted to bf16-hi, ds_write'd swizzled.
// B: Bbh staged via global_load_lds with pre-swizzled source.
// Out: X0 bf16 pair (exact split of computed f32), via LDS retile, int4 stores.
__global__ __launch_bounds__(256, 3) void k_bu(
    const float* __restrict__ u, const bf16* __restrict__ Bbh,
    bf16* __restrict__ Xoh, bf16* __restrict__ Xol)
{
    __shared__ char smem[32768];
    const int tid = threadIdx.x;
    const int wave = tid >> 6, lane = tid & 63;
    const int wm = wave >> 1, wn = wave & 1;
    const int rl = lane & 15, rh = lane >> 4;
    const long brow = (long)blockIdx.x * 128;
    const int bcol = blockIdx.y * 128;

    f32x4 acc[4][4];
#pragma unroll
    for (int m = 0; m < 4; ++m)
#pragma unroll
        for (int n = 0; n < 4; ++n) acc[m][n] = (f32x4){0.f, 0.f, 0.f, 0.f};

    // A: per chunk q, thread owns row=idx>>2, slot=idx&3 (8 f32 = 32B)
    const float* aptr[2]; int awoff[2];
    const char* pB[2]; int wb[2];
#pragma unroll
    for (int q = 0; q < 2; ++q) {
        int idx = q * 256 + tid;
        int row = idx >> 2, slot = idx & 3;
        int sp = slot ^ ((row >> 1) & 3);
        aptr[q] = u + (brow + row) * N + slot * 8;
        awoff[q] = row * 64 + sp * 16;
        pB[q] = (const char*)(Bbh + (long)(bcol + row) * N + sp * 8);
        wb[q] = (q * 256 + wave * 64) * 16;
    }

    auto stageA = [&](int t, char* buf) {
#pragma unroll
        for (int q = 0; q < 2; ++q) {
            f32x4 v0 = *reinterpret_cast<const f32x4*>(aptr[q] + t * 32);
            f32x4 v1 = *reinterpret_cast<const f32x4*>(aptr[q] + t * 32 + 4);
            s16x8 h;
            h[0] = (short)f2h(v0[0]); h[1] = (short)f2h(v0[1]);
            h[2] = (short)f2h(v0[2]); h[3] = (short)f2h(v0[3]);
            h[4] = (short)f2h(v1[0]); h[5] = (short)f2h(v1[1]);
            h[6] = (short)f2h(v1[2]); h[7] = (short)f2h(v1[3]);
            *reinterpret_cast<s16x8*>(buf + awoff[q]) = h;
        }
    };
    auto stageB = [&](int t, char* buf) {
#pragma unroll
        for (int q = 0; q < 2; ++q) gload16(pB[q] + t * 64, buf + 8192 + wb[q]);
    };

    stageA(0, smem);
    stageB(0, smem);
    __syncthreads();

    for (int t = 0; t < 16; ++t) {
        const char* base = smem + (t & 1) * 16384;
        s16x8 a[4], b[4];
#pragma unroll
        for (int m = 0; m < 4; ++m) {
            int row = wm * 64 + m * 16 + rl;
            a[m] = *reinterpret_cast<const s16x8*>(base + row * 64 + (rh ^ ((row >> 1) & 3)) * 16);
        }
#pragma unroll
        for (int n = 0; n < 4; ++n) {
            int row = wn * 64 + n * 16 + rl;
            b[n] = *reinterpret_cast<const s16x8*>(base + 8192 + row * 64 + (rh ^ ((row >> 1) & 3)) * 16);
        }
        if (t + 1 < 16) {
            char* nb = smem + ((t + 1) & 1) * 16384;
            stageA(t + 1, nb);
            stageB(t + 1, nb);
        }
#pragma unroll
        for (int m = 0; m < 4; ++m)
#pragma unroll
            for (int n = 0; n < 4; ++n)
                acc[m][n] = __builtin_amdgcn_mfma_f32_16x16x32_bf16(a[m], b[n], acc[m][n], 0, 0, 0);
        __syncthreads();
    }

    // vectorized epilogue via LDS retile (two 64-row halves)
    float* eld = (float*)smem;
    const int erow = tid >> 2;
    const int ec   = (tid & 3) * 8;
    for (int h = 0; h < 2; ++h) {
        if (wm == h) {
#pragma unroll
            for (int m = 0; m < 4; ++m)
#pragma unroll
                for (int q = 0; q < 4; ++q) {
                    int br = m * 16 + rh * 4 + q;
                    int sw = (br & 7) << 2;
#pragma unroll
                    for (int n = 0; n < 4; ++n) {
                        int col = wn * 64 + n * 16 + rl;
                        eld[br * 128 + (col ^ sw)] = acc[m][n][q];
                    }
                }
        }
        __syncthreads();
        {
            long gi = brow + h * 64 + erow;
            const int sw = (erow & 7) << 2;
            long gb = gi * N + bcol;
#pragma unroll
            for (int s = 0; s < 4; ++s) {
                int c = ec + s * 32;
                f32x4 v0 = *reinterpret_cast<const f32x4*>(&eld[erow * 128 + (c ^ sw)]);
                f32x4 v1 = *reinterpret_cast<const f32x4*>(&eld[erow * 128 + ((c ^ sw) ^ 4)]);
                float r[8];
                *reinterpret_cast<f32x4*>(&r[0]) = v0;
                *reinterpret_cast<f32x4*>(&r[4]) = v1;
                ushort oh[8], ol[8];
#pragma unroll
                for (int j = 0; j < 8; ++j) split2(r[j], oh[j], ol[j]);
                *reinterpret_cast<int4*>(Xoh + gb + c) = *reinterpret_cast<int4*>(oh);
                *reinterpret_cast<int4*>(Xol + gb + c) = *reinterpret_cast<int4*>(ol);
            }
        }
        __syncthreads();
    }
}

// ---------------- k_fin: y = X_hi @ C_hi^T (f32 out), NM=1 -------------------
__global__ __launch_bounds__(256, 3) void k_fin(
    const bf16* __restrict__ Xh, const bf16* __restrict__ Ch, float* __restrict__ Of)
{
    __shared__ char smem[32768];
    const int tid = threadIdx.x;
    const int wave = tid >> 6, lane = tid & 63;
    const int wm = wave >> 1, wn = wave & 1;
    const int rl = lane & 15, rh = lane >> 4;
    const long brow = (long)blockIdx.x * 128;
    const int bcol = blockIdx.y * 128;

    f32x4 acc[4][4];
#pragma unroll
    for (int m = 0; m < 4; ++m)
#pragma unroll
        for (int n = 0; n < 4; ++n) acc[m][n] = (f32x4){0.f, 0.f, 0.f, 0.f};

    const char* pA[2]; const char* pB[2]; int wb[2];
#pragma unroll
    for (int q = 0; q < 2; ++q) {
        int idx = q * 256 + tid;
        int row = idx >> 2, slot = idx & 3;
        int sp = slot ^ ((row >> 1) & 3);
        pA[q] = (const char*)(Xh + (brow + row) * N + sp * 8);
        pB[q] = (const char*)(Ch + (long)(bcol + row) * N + sp * 8);
        wb[q] = (q * 256 + wave * 64) * 16;
    }

#pragma unroll
    for (int q = 0; q < 2; ++q) {
        gload16(pA[q], smem + 0    + wb[q]);
        gload16(pB[q], smem + 8192 + wb[q]);
    }
    __syncthreads();

    for (int t = 0; t < 16; ++t) {
        const char* base = smem + (t & 1) * 16384;
        s16x8 a[4], b[4];
#pragma unroll
        for (int m = 0; m < 4; ++m) {
            int row = wm * 64 + m * 16 + rl;
            a[m] = *reinterpret_cast<const s16x8*>(base + row * 64 + (rh ^ ((row >> 1) & 3)) * 16);
        }
#pragma unroll
        for (int n = 0; n < 4; ++n) {
            int row = wn * 64 + n * 16 + rl;
            b[n] = *reinterpret_cast<const s16x8*>(base + 8192 + row * 64 + (rh ^ ((row >> 1) & 3)) * 16);
        }
        if (t + 1 < 16) {
            const int kb = (t + 1) * 64;
            char* nb = smem + ((t + 1) & 1) * 16384;
#pragma unroll
            for (int q = 0; q < 2; ++q) {
                gload16(pA[q] + kb, nb + 0    + wb[q]);
                gload16(pB[q] + kb, nb + 8192 + wb[q]);
            }
        }
#pragma unroll
        for (int m = 0; m < 4; ++m)
#pragma unroll
            for (int n = 0; n < 4; ++n)
                acc[m][n] = __builtin_amdgcn_mfma_f32_16x16x32_bf16(a[m], b[n], acc[m][n], 0, 0, 0);
        __syncthreads();
    }

    // vectorized f32 epilogue via LDS retile
    float* eld = (float*)smem;
    const int erow = tid >> 2;
    const int ec   = (tid & 3) * 8;
    for (int h = 0; h < 2; ++h) {
        if (wm == h) {
#pragma unroll
            for (int m = 0; m < 4; ++m)
#pragma unroll
                for (int q = 0; q < 4; ++q) {
                    int br = m * 16 + rh * 4 + q;
                    int sw = (br & 7) << 2;
#pragma unroll
                    for (int n = 0; n < 4; ++n) {
                        int col = wn * 64 + n * 16 + rl;
                        eld[br * 128 + (col ^ sw)] = acc[m][n][q];
                    }
                }
        }
        __syncthreads();
        {
            long gi = brow + h * 64 + erow;
            const int sw = (erow & 7) << 2;
            long gb = gi * N + bcol;
#pragma unroll
            for (int s = 0; s < 4; ++s) {
                int c = ec + s * 32;
                f32x4 v0 = *reinterpret_cast<const f32x4*>(&eld[erow * 128 + (c ^ sw)]);
                f32x4 v1 = *reinterpret_cast<const f32x4*>(&eld[erow * 128 + ((c ^ sw) ^ 4)]);
                *reinterpret_cast<f32x4*>(Of + gb + c)     = v0;
                *reinterpret_cast<f32x4*>(Of + gb + c + 4) = v1;
            }
        }
        __syncthreads();
    }
}

// ---------------- k_drnd: D-form doubling round (unchanged from r9) -----------
__global__ __launch_bounds__(256, 3) void k_drnd(
    const bf16* __restrict__ Xih, const bf16* __restrict__ Xil,
    bf16* __restrict__ Xoh, bf16* __restrict__ Xol,
    const bf16* __restrict__ Dh, const bf16* __restrict__ Dl,
    const bf16* __restrict__ DTh, const bf16* __restrict__ DTl,
    const float* __restrict__ DTf,
    bf16* __restrict__ Dnh, bf16* __restrict__ Dnl,
    bf16* __restrict__ DTnh, bf16* __restrict__ DTnl, float* __restrict__ DTfn,
    int shift, int doSq, const bf16* __restrict__ zb)
{
    __shared__ char smem[32768];
    const int tid = threadIdx.x;
    const int wave = tid >> 6, lane = tid & 63;
    const int wm = wave >> 1, wn = wave & 1;
    const int rl = lane & 15, rh = lane >> 4;

    if (blockIdx.x < SQX) {
        if (!doSq) return;
        int sidx = (int)blockIdx.x * (int)gridDim.y + (int)blockIdx.y;  // 0..63
        const int ti = (sidx >> 3) * 64, tj = (sidx & 7) * 64;

        f32x4 acc[2][2];
#pragma unroll
        for (int m = 0; m < 2; ++m)
#pragma unroll
            for (int n = 0; n < 2; ++n) acc[m][n] = (f32x4){0.f, 0.f, 0.f, 0.f};

        int row = tid >> 2, slot = tid & 3;
        int sp = slot ^ ((row >> 1) & 3);
        const char* pAh = (const char*)(DTh + (size_t)(ti + row) * N + sp * 8);
        const char* pAl = (const char*)(DTl + (size_t)(ti + row) * N + sp * 8);
        const char* pBh = (const char*)(Dh + (size_t)(tj + row) * N + sp * 8);
        const char* pBl = (const char*)(Dl + (size_t)(tj + row) * N + sp * 8);
        const int wb = wave * 1024;

        gload16(pAh, smem + 0     + wb);
        gload16(pAl, smem + 4096  + wb);
        gload16(pBh, smem + 8192  + wb);
        gload16(pBl, smem + 12288 + wb);
        __syncthreads();

        for (int t = 0; t < 16; ++t) {
            const char* base = smem + (t & 1) * 16384;
            s16x8 ah[2], al[2], bh[2], bl[2];
#pragma unroll
            for (int m = 0; m < 2; ++m) {
                int r2 = wm * 32 + m * 16 + rl;
                int off = r2 * 64 + (rh ^ ((r2 >> 1) & 3)) * 16;
                ah[m] = *reinterpret_cast<const s16x8*>(base + off);
                al[m] = *reinterpret_cast<const s16x8*>(base + 4096 + off);
            }
#pragma unroll
            for (int n = 0; n < 2; ++n) {
                int r2 = wn * 32 + n * 16 + rl;
                int off = r2 * 64 + (rh ^ ((r2 >> 1) & 3)) * 16;
                bh[n] = *reinterpret_cast<const s16x8*>(base + 8192 + off);
                bl[n] = *reinterpret_cast<const s16x8*>(base + 12288 + off);
            }
            if (t + 1 < 16) {
                const int kb = (t + 1) * 64;
                char* nb = smem + ((t + 1) & 1) * 16384;
                gload16(pAh + kb, nb + 0     + wb);
                gload16(pAl + kb, nb + 4096  + wb);
                gload16(pBh + kb, nb + 8192  + wb);
                gload16(pBl + kb, nb + 12288 + wb);
            }
#pragma unroll
            for (int m = 0; m < 2; ++m)
#pragma unroll
                for (int n = 0; n < 2; ++n) {
                    acc[m][n] = __builtin_amdgcn_mfma_f32_16x16x32_bf16(ah[m], bh[n], acc[m][n], 0, 0, 0);
                    acc[m][n] = __builtin_amdgcn_mfma_f32_16x16x32_bf16(ah[m], bl[n], acc[m][n], 0, 0, 0);
                    acc[m][n] = __builtin_amdgcn_mfma_f32_16x16x32_bf16(al[m], bh[n], acc[m][n], 0, 0, 0);
                }
            __syncthreads();
        }

#pragma unroll
        for (int m = 0; m < 2; ++m)
#pragma unroll
            for (int n = 0; n < 2; ++n)
#pragma unroll
                for (int q = 0; q < 4; ++q) {
                    int i = ti + wm * 32 + m * 16 + rh * 4 + q;
                    int j = tj + wn * 32 + n * 16 + rl;
                    size_t off = (size_t)i * N + j;
                    float v = acc[m][n][q] + 2.0f * DTf[off];   // (D^2)^T + 2 D^T
                    DTfn[off] = v;
                    ushort h, l;
                    split2(v, h, l);
                    *reinterpret_cast<ushort*>(DTnh + off) = h;
                    *reinterpret_cast<ushort*>(DTnl + off) = l;
                    size_t offT = (size_t)j * N + i;
                    *reinterpret_cast<ushort*>(Dnh + offT) = h;
                    *reinterpret_cast<ushort*>(Dnl + offT) = l;
                }
        return;
    }

    // big path (rows rotated so GEMM blocks dispatch first)
    int bigbx = (int)blockIdx.x - SQX;
    const int sb = shift >> 7;
    int rowBlk = bigbx + sb;
    bool isCopy = false;
    if (rowBlk >= (L / 128)) { rowBlk -= (L / 128); isCopy = true; }
    const long brow = (long)rowBlk * 128;
    const int bcol = blockIdx.y * 128;

    if (isCopy) {
#pragma unroll
        for (int j = 0; j < 8; ++j) {
            int c = j * 256 + tid;
            long off = (brow + (c >> 4)) * N + bcol + (c & 15) * 8;
            *reinterpret_cast<int4*>(Xoh + off) = *reinterpret_cast<const int4*>(Xih + off);
            *reinterpret_cast<int4*>(Xol + off) = *reinterpret_cast<const int4*>(Xil + off);
        }
        return;
    }

    f32x4 acc[4][4];
#pragma unroll
    for (int m = 0; m < 4; ++m)
#pragma unroll
        for (int n = 0; n < 4; ++n) acc[m][n] = (f32x4){0.f, 0.f, 0.f, 0.f};

    const char* pA[2]; const char* pB[2]; int wb[2];
#pragma unroll
    for (int q = 0; q < 2; ++q) {
        int idx = q * 256 + tid;
        int row = idx >> 2, slot = idx & 3;
        int sp = slot ^ ((row >> 1) & 3);
        long gra = brow + row - (long)shift;
        pA[q] = (gra >= 0) ? (const char*)(Xih + gra * N + sp * 8)
                           : (const char*)(zb + sp * 8);
        pB[q] = (const char*)(Dh + (long)(bcol + row) * N + sp * 8);
        wb[q] = (q * 256 + wave * 64) * 16;
    }

#pragma unroll
    for (int q = 0; q < 2; ++q) {
        gload16(pA[q], smem + 0    + wb[q]);
        gload16(pB[q], smem + 8192 + wb[q]);
    }
    __syncthreads();

    for (int t = 0; t < 16; ++t) {
        const char* base = smem + (t & 1) * 16384;
        s16x8 a[4], b[4];
#pragma unroll
        for (int m = 0; m < 4; ++m) {
            int row = wm * 64 + m * 16 + rl;
            a[m] = *reinterpret_cast<const s16x8*>(base + row * 64 + (rh ^ ((row >> 1) & 3)) * 16);
        }
#pragma unroll
        for (int n = 0; n < 4; ++n) {
            int row = wn * 64 + n * 16 + rl;
            b[n] = *reinterpret_cast<const s16x8*>(base + 8192 + row * 64 + (rh ^ ((row >> 1) & 3)) * 16);
        }
        if (t + 1 < 16) {
            const int kb = (t + 1) * 64;
            char* nb = smem + ((t + 1) & 1) * 16384;
#pragma unroll
            for (int q = 0; q < 2; ++q) {
                gload16(pA[q] + kb, nb + 0    + wb[q]);
                gload16(pB[q] + kb, nb + 8192 + wb[q]);
            }
        }
#pragma unroll
        for (int m = 0; m < 4; ++m)
#pragma unroll
            for (int n = 0; n < 4; ++n)
                acc[m][n] = __builtin_amdgcn_mfma_f32_16x16x32_bf16(a[m], b[n], acc[m][n], 0, 0, 0);
        __syncthreads();
    }

    // vectorized epilogue via LDS retile (two 64-row halves)
    float* eld = (float*)smem;
    const int erow = tid >> 2;
    const int ec   = (tid & 3) * 8;
    for (int h = 0; h < 2; ++h) {
        if (wm == h) {
#pragma unroll
            for (int m = 0; m < 4; ++m)
#pragma unroll
                for (int q = 0; q < 4; ++q) {
                    int br = m * 16 + rh * 4 + q;
                    int sw = (br & 7) << 2;
#pragma unroll
                    for (int n = 0; n < 4; ++n) {
                        int col = wn * 64 + n * 16 + rl;
                        eld[br * 128 + (col ^ sw)] = acc[m][n][q];
                    }
                }
        }
        __syncthreads();
        {
            long gi = brow + h * 64 + erow;
            bool hasS = gi >= (long)shift;
            const int sw = (erow & 7) << 2;
            long gb = gi * N + bcol;
            long gs = gb - (long)shift * N;
#pragma unroll
            for (int s = 0; s < 4; ++s) {
                int c = ec + s * 32;
                f32x4 v0 = *reinterpret_cast<const f32x4*>(&eld[erow * 128 + (c ^ sw)]);
                f32x4 v1 = *reinterpret_cast<const f32x4*>(&eld[erow * 128 + ((c ^ sw) ^ 4)]);
                float r[8];
                *reinterpret_cast<f32x4*>(&r[0]) = v0;
                *reinterpret_cast<f32x4*>(&r[4]) = v1;
                ushort vh[8], vl[8];
                *reinterpret_cast<int4*>(vh) = *reinterpret_cast<const int4*>(Xih + gb + c);
                *reinterpret_cast<int4*>(vl) = *reinterpret_cast<const int4*>(Xil + gb + c);
#pragma unroll
                for (int j = 0; j < 8; ++j) r[j] += us2f(vh[j]) + us2f(vl[j]);
                if (hasS) {
                    *reinterpret_cast<int4*>(vh) = *reinterpret_cast<const int4*>(Xih + gs + c);
                    *reinterpret_cast<int4*>(vl) = *reinterpret_cast<const int4*>(Xil + gs + c);
#pragma unroll
                    for (int j = 0; j < 8; ++j) r[j] += us2f(vh[j]) + us2f(vl[j]);
                }
                ushort oh[8], ol[8];
#pragma unroll
                for (int j = 0; j < 8; ++j) split2(r[j], oh[j], ol[j]);
                *reinterpret_cast<int4*>(Xoh + gb + c) = *reinterpret_cast<int4*>(oh);
                *reinterpret_cast<int4*>(Xol + gb + c) = *reinterpret_cast<int4*>(ol);
            }
        }
        __syncthreads();
    }
}

// ---------------- launcher ----------------

extern "C" void kernel_launch(void* const* d_in, const int* in_sizes, int n_in,
                              void* d_out, int out_size, void* d_ws, size_t ws_size,
                              hipStream_t stream) {
    (void)in_sizes; (void)n_in; (void)out_size; (void)ws_size;
    const float* A = (const float*)d_in[0];
    const float* B = (const float*)d_in[1];
    const float* C = (const float*)d_in[2];
    const float* u = (const float*)d_in[3];

    const size_t NN = (size_t)N * N;
    const size_t LN = (size_t)L * N;

    // X1 pair lives in d_out (2 x 16.8MB bf16 == 33.6MB f32 out buffer)
    bf16* X1h = (bf16*)d_out;
    bf16* X1l = X1h + LN;

    char* w = (char*)d_ws;
    bf16* X0h = (bf16*)w;      w += LN * 2;
    bf16* X0l = (bf16*)w;      w += LN * 2;
    bf16 *Dh_[2], *Dl_[2], *DTh_[2], *DTl_[2];
    float* DTf_[2];
    for (int s = 0; s < 2; ++s) {
        Dh_[s]  = (bf16*)w;    w += NN * 2;
        Dl_[s]  = (bf16*)w;    w += NN * 2;
        DTh_[s] = (bf16*)w;    w += NN * 2;
        DTl_[s] = (bf16*)w;    w += NN * 2;
        DTf_[s] = (float*)w;   w += NN * 4;
    }
    float* M   = (float*)w;    w += NN * 4;
    float* MT  = (float*)w;    w += NN * 4;
    float* M2  = (float*)w;    w += NN * 4;
    float* BLm = (float*)w;    w += NN * 4;
    float* BT  = (float*)w;    w += NN * 4;
    float* Bbf = (float*)w;    w += NN * 4;
    bf16* Bbh  = (bf16*)w;     w += NN * 2;
    bf16* Bbl  = (bf16*)w;     w += NN * 2;
    bf16* Ch   = (bf16*)w;     w += NN * 2;
    bf16* Cl   = (bf16*)w;     w += NN * 2;
    bf16* zb   = (bf16*)w;     w += 2048;

    const float step = 1.0f / (float)L;

    dim3 b256(256);
    dim3 bT(32, 8), gT(N / 32, N / 32);
    dim3 g64(N / 64, N / 64);
    dim3 gBig(L / 128, N / 128);
    dim3 gRound(SQX + L / 128, N / 128);   // sq blocks first, then 128 big rows
    dim3 gS4n((int)(NN / 4 / 256));

    k_zeroinit<<<2, 256, 0, stream>>>((int*)zb);

    // ---- setup (fused) ----
    k_prep<<<gT, bT, 0, stream>>>(A, M, MT, step * 0.5f);                   // M, M^T
    k_qsq<<<g64, b256, 0, stream>>>(M, MT, M2, Bbh, Bbl, 1.0f);             // M2 = M@M (splits scratch)
    k_buildDT<<<gT, bT, 0, stream>>>(M, M2, Dh_[0], Dl_[0],
                                     DTf_[0], DTh_[0], DTl_[0], BLm);       // D_0 both orientations, BL
    k_transpose<<<gT, bT, 0, stream>>>(B, BT);
    k_qsq<<<g64, b256, 0, stream>>>(BLm, BT, Bbf, Bbh, Bbl, step);          // Bb (+ split)
    k_split4<<<gS4n, b256, 0, stream>>>(C, Ch, Cl, (int)(NN / 4));

    // ---- Bu = u @ Bb^T -> X0 pair (NM=1, u reg-staged from f32) ----
    k_bu<<<gBig, b256, 0, stream>>>(u, Bbh, X0h, X0l);

    // ---- 14 doubling rounds, all NM=1 D-form (sq fused, copies last) ----
    for (int r = 0; r < 14; ++r) {
        int s = r & 1, nx = s ^ 1;
        bf16* Xih = (r & 1) ? X1h : X0h;  bf16* Xil = (r & 1) ? X1l : X0l;
        bf16* Xoh = (r & 1) ? X0h : X1h;  bf16* Xol = (r & 1) ? X0l : X1l;
        int doSq = (r < 13) ? 1 : 0;
        k_drnd<<<gRound, b256, 0, stream>>>(
            Xih, Xil, Xoh, Xol, Dh_[s], Dl_[s],
            DTh_[s], DTl_[s], DTf_[s],
            Dh_[nx], Dl_[nx], DTh_[nx], DTl_[nx], DTf_[nx], 1 << r, doSq, zb);
    }

    // ---- final: OUT = X0_hi @ C_hi^T (f32, overwrites d_out; X1 dead) ----
    k_fin<<<gBig, b256, 0, stream>>>(X0h, Ch, (float*)d_out);
}